// Round 16
// baseline (322.155 us; speedup 1.0000x reference)
//
#include <hip/hip_runtime.h>
#include <hip/hip_bf16.h>

#define A_DIM 200
#define F_DIM 53
#define NAF 38
#define NPHYS 15
#define R_OUT 20
#define C_OUT 1024
#define BLOCK 256
#define HPAD 40      // ushort row stride of LDS tile
#define MROWS 208
#define NSPL 4       // row splits per batch
#define KP 24        // wcT k-stride (k>=20 zeroed)
#define WCB ((C_OUT * KP + 255) / 256)

typedef __attribute__((ext_vector_type(8))) short short8;
typedef __attribute__((ext_vector_type(4))) float floatx4;

__device__ __forceinline__ float bf2f(ushort u) { return __uint_as_float((uint)u << 16); }
__device__ __forceinline__ ushort f2bf(float f) {
    union { __hip_bfloat16 h; ushort u; } cv; cv.h = __float2bfloat16(f); return cv.u;
}

// standalone wcT prep (fallback tier only)
__global__ void wc_prep(const float* __restrict__ Wc, ushort* __restrict__ wcT) {
    const int i = blockIdx.x * 256 + threadIdx.x;
    if (i >= C_OUT * KP) return;
    const int col = i / KP, k = i - col * KP;
    wcT[i] = f2bf((k < R_OUT) ? Wc[k * C_OUT + col] : 0.f);
}

// ===== A: [0,nB): agg->hnei+physics+cnt=0 | [nB,nB+WCB): wcT | nB+WCB: wsfrag =====
__global__ __launch_bounds__(256, 8) void pggcn_prep(
    const float* __restrict__ inputs,
    const int*   __restrict__ i_s,
    const float* __restrict__ W_self,
    const float* __restrict__ W_nei,
    const float* __restrict__ b_r,
    const float* __restrict__ Wc,
    float* __restrict__ hneip,    // [B][32]
    ushort* __restrict__ wcT,     // [1024][24]
    ushort* __restrict__ wsfrag,  // [64][4] short8 = 4 KB
    int* __restrict__ cnt,        // [B] arrival counters (zeroed here each call)
    float* __restrict__ out,
    int nB)
{
    __shared__ float s_aggp[4 * 56];
    __shared__ float s_agg[NAF];
    const int bx = blockIdx.x, t = threadIdx.x;

    if (bx >= nB) {
        if (bx == nB + WCB) {
            // W_self B-frag table: consumer lane l, frag q: q0/q1 = bws0[0/1],
            // q2/q3 = bws1[0/1]
            const int l = t >> 2, q = t & 3;
            const int lr = l & 15, lg = l >> 4;
            const int nt = q & 1, ks = q >> 1;
            const int c = nt * 16 + lr;
            short8 v;
            #pragma unroll
            for (int j = 0; j < 8; ++j) {
                const int k = ks * 32 + lg * 8 + j;
                const bool p = (c < R_OUT) && (k < NAF);
                v[j] = (short)(p ? f2bf(W_self[k * R_OUT + c]) : 0);
            }
            *(short8*)&wsfrag[(size_t)t * 8] = v;
            return;
        }
        const int i = (bx - nB) * 256 + t;   // wcT conversion chunk
        if (i < C_OUT * KP) {
            const int col = i / KP, k = i - col * KP;
            wcT[i] = f2bf((k < R_OUT) ? Wc[k * C_OUT + col] : 0.f);
        }
        return;
    }

    const int b = bx;
    const int ns = i_s[b];
    const float* in_b = inputs + (size_t)b * (A_DIM * F_DIM);

    if (t < NPHYS) out[(size_t)b * 16 + 1 + t] = in_b[NAF + t];
    if (t == 32) cnt[b] = 0;   // reset arrival counter every call (graph-safe)

    // 4 row-groups x 53 cols, 4-deep batched loads
    if (t < 4 * F_DIM) {
        const int g = t / F_DIM, c = t - g * F_DIM;
        const float* p = in_b + g * F_DIM + c;
        float s = 0.f;
        int r = g;
        for (; r + 16 <= ns; r += 16) {
            const float v0 = p[0], v1 = p[4 * F_DIM], v2 = p[8 * F_DIM], v3 = p[12 * F_DIM];
            s += (v0 + v1) + (v2 + v3);
            p += 16 * F_DIM;
        }
        for (; r < ns; r += 4) { s += *p; p += 4 * F_DIM; }
        s_aggp[g * 56 + c] = s;
    }
    __syncthreads();
    if (t < NAF) s_agg[t] = (s_aggp[t] + s_aggp[56 + t]) + (s_aggp[112 + t] + s_aggp[168 + t]);
    __syncthreads();
    if (t < 32) {
        float s = 0.f;
        if (t < R_OUT) {
            s = b_r[t];
            #pragma unroll
            for (int f = 0; f < NAF; ++f) s += s_agg[f] * W_nei[f * R_OUT + t];
        }
        hneip[(size_t)b * 32 + t] = s;
    }
}

// ===== B: row-quarter blocks -> partial pooled (bf16); LAST block per batch
//       fuses the tail (sum splits -> d1 -> d5 -> out0) =====
__global__ __launch_bounds__(256, 8) void pggcn_main(
    const float* __restrict__ inputs,
    const int*   __restrict__ i_s,
    const float* __restrict__ bc,
    const ushort* __restrict__ wcT,
    const ushort* __restrict__ wsfrag,
    const float* __restrict__ hneip,
    const float* __restrict__ W1,
    const float* __restrict__ b1,
    const float* __restrict__ W5,
    const float* __restrict__ b5,
    const float* __restrict__ W6,
    const float* __restrict__ b6,
    const float* __restrict__ W7,
    const float* __restrict__ b7,
    ushort* __restrict__ pooledp,
    int* __restrict__ cnt,
    float* __restrict__ out,
    int nB)
{
    __shared__ __align__(16) ushort s_hb[64 * HPAD];   // 5120 B (atoms -> h in place)
    __shared__ float s_redT[8 * 32];                   // tail: d1 partials
    __shared__ float s_d1T[32];
    __shared__ float s_d5T[16];
    __shared__ int s_old;
    float* s_pool = (float*)s_hb;                      // 1024 f alias (post-main)
    float* s_sum  = (float*)s_hb;                      // tail alias (after pack)

    const int bx    = blockIdx.x;
    const int split = bx / nB;           // 0..3 (split-major: all 4 on one XCD)
    const int b     = bx - split * nB;
    const int t     = threadIdx.x;
    const int lane  = t & 63;
    const int wv    = t >> 6;
    const int lr    = lane & 15;
    const int lg    = lane >> 4;
    const int ns    = i_s[b];
    const int nmt   = (ns + 15) >> 4;
    const int lt0   = (nmt * split) >> 2;
    const int lt1   = (nmt * (split + 1)) >> 2;
    const int ntl   = lt1 - lt0;         // 0..4 tiles
    ushort* outp = pooledp + ((size_t)(split * nB + b)) * 1024;

    if (ntl > 0) {
        const int row0  = lt0 * 16;
        const int nrows = ntl * 16;
        const float* in_b = inputs + (size_t)b * (A_DIM * F_DIM);

        const float hn0 = hneip[(size_t)b * 32 + lr];
        const float hn1 = hneip[(size_t)b * 32 + 16 + lr];

        // W_self B-frags: 4 coalesced 16B loads from the precomputed table
        const short8 bws00 = *(const short8*)&wsfrag[(size_t)(lane * 4 + 0) * 8];
        const short8 bws01 = *(const short8*)&wsfrag[(size_t)(lane * 4 + 1) * 8];
        const short8 bws10 = *(const short8*)&wsfrag[(size_t)(lane * 4 + 2) * 8];
        const short8 bws11 = *(const short8*)&wsfrag[(size_t)(lane * 4 + 3) * 8];

        // ---- stage valid rows bf16, thread-per-row-quad ----
        const int vloc = (ns - row0 < nrows) ? (ns - row0) : nrows;
        {
            const int r = t >> 2, q = t & 3;
            if (r < vloc) {
                const float* rp = in_b + (size_t)(row0 + r) * F_DIM + q * 10;
                uint* dst = (uint*)&s_hb[r * HPAD + q * 10];
                #pragma unroll
                for (int p = 0; p < 5; ++p) {
                    const uint lo = f2bf(rp[2 * p]);
                    const uint hi = f2bf(rp[2 * p + 1]);
                    dst[p] = lo | (hi << 16);
                }
            }
        }
        __syncthreads();

        // ---- h-MFMA in place: h = (row valid) ? relu(atom@W_self + hnei) : 0 ----
        for (int lt = wv; lt < ntl; lt += 4) {
            const int ar = lt * 16 + lr;
            const short8 a0 = *(const short8*)&s_hb[ar * HPAD + lg * 8];
            short8 a1 = short8{0, 0, 0, 0, 0, 0, 0, 0};
            if (lg == 0) a1 = *(const short8*)&s_hb[ar * HPAD + 32];
            floatx4 aS0 = {hn0, hn0, hn0, hn0};
            floatx4 aS1 = {hn1, hn1, hn1, hn1};
            aS0 = __builtin_amdgcn_mfma_f32_16x16x32_bf16(a0, bws00, aS0, 0, 0, 0);
            aS0 = __builtin_amdgcn_mfma_f32_16x16x32_bf16(a1, bws10, aS0, 0, 0, 0);
            aS1 = __builtin_amdgcn_mfma_f32_16x16x32_bf16(a0, bws01, aS1, 0, 0, 0);
            aS1 = __builtin_amdgcn_mfma_f32_16x16x32_bf16(a1, bws11, aS1, 0, 0, 0);
            // C/D: col = lane&15, row = (lane>>4)*4 + q
            #pragma unroll
            for (int q = 0; q < 4; ++q) {
                const int lrow = lt * 16 + lg * 4 + q;
                const bool vv = lrow < vloc;
                s_hb[lrow * HPAD + lr]      = vv ? f2bf(fmaxf(aS0[q], 0.f)) : (ushort)0;
                s_hb[lrow * HPAD + 16 + lr] = vv ? f2bf(fmaxf(aS1[q], 0.f)) : (ushort)0;
            }
        }

        // ---- main: partial pooled over own rows, all 1024 cols (4 rounds x 4) ----
        const float dead = (float)(nrows - vloc);
        float pool[16];
        #pragma unroll
        for (int i = 0; i < 16; ++i) pool[i] = 0.f;

        #pragma unroll 1
        for (int qt = 0; qt < 4; ++qt) {
            short8 bfr[4];
            float  bcv[4];
            #pragma unroll
            for (int nt = 0; nt < 4; ++nt) {
                const int col = wv * 256 + qt * 64 + nt * 16 + lr;
                bcv[nt] = bc[col];
                if (lg < 3) bfr[nt] = *(const short8*)&wcT[col * KP + lg * 8];
                else        bfr[nt] = short8{0, 0, 0, 0, 0, 0, 0, 0};
            }
            if (qt == 0) __syncthreads();   // h ready; frag-load latency overlapped

            for (int mt = 0; mt < ntl; ++mt) {
                const short8 af = *(const short8*)&s_hb[(mt * 16 + lr) * HPAD + lg * 8];
                #pragma unroll
                for (int nt = 0; nt < 4; ++nt) {
                    floatx4 acc = { bcv[nt], bcv[nt], bcv[nt], bcv[nt] };
                    acc = __builtin_amdgcn_mfma_f32_16x16x32_bf16(af, bfr[nt], acc, 0, 0, 0);
                    pool[qt * 4 + nt] += fmaxf(acc[0], 0.f) + fmaxf(acc[1], 0.f)
                                       + fmaxf(acc[2], 0.f) + fmaxf(acc[3], 0.f);
                }
            }
            if (lg == 0) {   // local dead rows contributed relu(bc) each
                #pragma unroll
                for (int nt = 0; nt < 4; ++nt)
                    pool[qt * 4 + nt] -= dead * fmaxf(bcv[nt], 0.f);
            }
        }
        #pragma unroll
        for (int i = 0; i < 16; ++i) {
            float p = pool[i];
            p += __shfl_xor(p, 16);
            p += __shfl_xor(p, 32);
            pool[i] = p;
        }
        __syncthreads();   // all s_hb reads done; alias safe
        if (lg == 0) {
            #pragma unroll
            for (int qt = 0; qt < 4; ++qt)
                #pragma unroll
                for (int nt = 0; nt < 4; ++nt)
                    s_pool[wv * 256 + qt * 64 + nt * 16 + lr] = pool[qt * 4 + nt];
        }
        __syncthreads();

        // ---- pack bf16 + one coalesced store ----
        const float4 pv = ((const float4*)s_pool)[t];
        ushort4 o;
        o.x = f2bf(pv.x); o.y = f2bf(pv.y); o.z = f2bf(pv.z); o.w = f2bf(pv.w);
        ((ushort4*)outp)[t] = o;
    } else {
        // no rows: publish exact zeros (still participates in arrival counter)
        ushort4 z = {0, 0, 0, 0};
        ((ushort4*)outp)[t] = z;
    }

    // ===== fused tail: last-arriving block of batch b finishes it =====
    __threadfence();
    if (t == 0) s_old = atomicAdd(&cnt[b], 1);
    __syncthreads();
    if (s_old != NSPL - 1) return;

    // sum the 4 split partials (bf16 -> fp32) into s_sum (s_hb alias; synced above)
    {
        const uint* q0 = (const uint*)(pooledp + (size_t)(0 * nB + b) * 1024);
        const uint* q1 = (const uint*)(pooledp + (size_t)(1 * nB + b) * 1024);
        const uint* q2 = (const uint*)(pooledp + (size_t)(2 * nB + b) * 1024);
        const uint* q3 = (const uint*)(pooledp + (size_t)(3 * nB + b) * 1024);
        for (int i = t; i < 512; i += 256) {
            const uint u0 = q0[i], u1 = q1[i], u2 = q2[i], u3 = q3[i];
            s_sum[2 * i] = (bf2f((ushort)u0) + bf2f((ushort)u1))
                         + (bf2f((ushort)u2) + bf2f((ushort)u3));
            s_sum[2 * i + 1] = (bf2f((ushort)(u0 >> 16)) + bf2f((ushort)(u1 >> 16)))
                             + (bf2f((ushort)(u2 >> 16)) + bf2f((ushort)(u3 >> 16)));
        }
    }
    __syncthreads();

    // d1 partials: 8 parts x 128 j
    {
        const int m = t & 31, part = t >> 5;
        const float4* pp = (const float4*)&s_sum[part * 128];
        const float* wrow = W1 + (size_t)(part * 128) * 32 + m;
        float s = 0.f;
        #pragma unroll
        for (int jq = 0; jq < 32; ++jq) {
            const float4 pv = pp[jq];
            s += pv.x * wrow[0] + pv.y * wrow[32] + pv.z * wrow[64] + pv.w * wrow[96];
            wrow += 128;
        }
        s_redT[part * 32 + m] = s;
    }
    __syncthreads();
    if (t < 32) {
        float s = b1[t];
        #pragma unroll
        for (int p = 0; p < 8; ++p) s += s_redT[p * 32 + t];
        s_d1T[t] = fmaxf(s, 0.f);
    }
    __syncthreads();
    if (t < 16) {
        float s = b5[t];
        #pragma unroll
        for (int m = 0; m < 32; ++m) s += s_d1T[m] * W5[m * 16 + t];
        s_d5T[t] = fmaxf(s, 0.f);
    }
    __syncthreads();
    if (t == 0) {
        float mv = b6[0];
        #pragma unroll
        for (int m = 0; m < 16; ++m) mv += s_d5T[m] * W6[m];
        float o = b7[0] + W7[0] * mv;
        const float* ph = inputs + (size_t)b * (A_DIM * F_DIM) + NAF;
        #pragma unroll
        for (int i = 0; i < NPHYS; ++i) o += W7[i + 1] * ph[i];
        out[(size_t)b * 16] = o;
    }
}

// ===== fallback (R11-proven single-kernel pipeline) =====
template <bool USE_WS>
__global__ __launch_bounds__(BLOCK, 4) void pggcn_kernel(
    const float* __restrict__ inputs,
    const int*   __restrict__ i_s,
    const float* __restrict__ W_self,
    const float* __restrict__ W_nei,
    const float* __restrict__ b_r,
    const float* __restrict__ Wc,
    const float* __restrict__ bc,
    const float* __restrict__ W1,
    const float* __restrict__ b1,
    const float* __restrict__ W5,
    const float* __restrict__ b5,
    const float* __restrict__ W6,
    const float* __restrict__ b6,
    const float* __restrict__ W7,
    const float* __restrict__ b7,
    const ushort* __restrict__ wcT,
    float* __restrict__ out)
{
    __shared__ __align__(16) ushort s_hb[MROWS * HPAD];
    __shared__ float s_aggp[6 * 40];
    __shared__ float s_agg[40];
    __shared__ float s_hnei[32];
    __shared__ float s_phys[NPHYS];

    float* s_pool = (float*)s_hb;
    float* s_red  = (float*)s_hb + 1024;
    float* s_d1   = s_red + 256;
    float* s_d5   = s_d1 + 32;

    const int b    = blockIdx.x;
    const int t    = threadIdx.x;
    const int lane = t & 63;
    const int wv   = t >> 6;
    const int lr   = lane & 15;
    const int lg   = lane >> 4;
    const int ns   = i_s[b];
    const int nmt  = (ns + 15) >> 4;
    const float* in_b = inputs + (size_t)b * (A_DIM * F_DIM);

    short8 bws0[2], bws1[2];
    #pragma unroll
    for (int nt = 0; nt < 2; ++nt) {
        const int c = nt * 16 + lr;
        const bool cv_ = (c < R_OUT);
        #pragma unroll
        for (int j = 0; j < 8; ++j) {
            const int k0 = lg * 8 + j;
            const int k1 = 32 + lg * 8 + j;
            bws0[nt][j] = (short)(cv_ ? f2bf(W_self[k0 * R_OUT + c]) : 0);
            bws1[nt][j] = (short)((cv_ && k1 < NAF) ? f2bf(W_self[k1 * R_OUT + c]) : 0);
        }
    }

    if (t < NPHYS) {
        const float p = in_b[NAF + t];
        s_phys[t] = p;
        out[(size_t)b * 16 + 1 + t] = p;
    }

    const int tot = nmt * 16 * HPAD;
    for (int i = t; i < tot; i += BLOCK) {
        const int r = i / HPAD;
        const int f = i - r * HPAD;
        const float v = (r < ns && f < NAF) ? in_b[r * F_DIM + f] : 0.f;
        s_hb[i] = f2bf(v);
    }
    __syncthreads();

    if (t < 240) {
        const int f = t % 40, g = t / 40;
        float s = 0.f;
        for (int r = g; r < ns; r += 6) s += bf2f(s_hb[r * HPAD + f]);
        s_aggp[g * 40 + f] = s;
    }
    __syncthreads();
    if (t < 40) {
        float s = 0.f;
        #pragma unroll
        for (int g = 0; g < 6; ++g) s += s_aggp[g * 40 + t];
        s_agg[t] = s;
    }
    __syncthreads();
    if (t < 32) {
        float s = 0.f;
        if (t < R_OUT) {
            s = b_r[t];
            #pragma unroll
            for (int f = 0; f < NAF; ++f) s += s_agg[f] * W_nei[f * R_OUT + t];
        }
        s_hnei[t] = s;
    }
    __syncthreads();

    for (int mt = wv; mt < nmt; mt += 4) {
        const int ar = mt * 16 + lr;
        const short8 a0 = *(const short8*)&s_hb[ar * HPAD + lg * 8];
        short8 a1 = short8{0, 0, 0, 0, 0, 0, 0, 0};
        if (lg == 0) a1 = *(const short8*)&s_hb[ar * HPAD + 32];
        const float hn0 = s_hnei[lr];
        const float hn1 = s_hnei[16 + lr];
        floatx4 aS0 = {hn0, hn0, hn0, hn0};
        floatx4 aS1 = {hn1, hn1, hn1, hn1};
        aS0 = __builtin_amdgcn_mfma_f32_16x16x32_bf16(a0, bws0[0], aS0, 0, 0, 0);
        aS0 = __builtin_amdgcn_mfma_f32_16x16x32_bf16(a1, bws1[0], aS0, 0, 0, 0);
        aS1 = __builtin_amdgcn_mfma_f32_16x16x32_bf16(a0, bws0[1], aS1, 0, 0, 0);
        aS1 = __builtin_amdgcn_mfma_f32_16x16x32_bf16(a1, bws1[1], aS1, 0, 0, 0);
        #pragma unroll
        for (int q = 0; q < 4; ++q) {
            const int row = mt * 16 + lg * 4 + q;
            const bool v = (row < ns);
            s_hb[row * HPAD + lr]      = v ? f2bf(fmaxf(aS0[q], 0.f)) : (ushort)0;
            s_hb[row * HPAD + 16 + lr] = v ? f2bf(fmaxf(aS1[q], 0.f)) : (ushort)0;
        }
    }

    const float dead = (float)(nmt * 16 - ns);
    float pool[16];
    #pragma unroll
    for (int i = 0; i < 16; ++i) pool[i] = 0.f;

    #pragma unroll 1
    for (int qt = 0; qt < 4; ++qt) {
        short8 bfr[4];
        float  bcv[4];
        #pragma unroll
        for (int nt = 0; nt < 4; ++nt) {
            const int col = wv * 256 + qt * 64 + nt * 16 + lr;
            bcv[nt] = bc[col];
            if (USE_WS) {
                if (lg < 3) bfr[nt] = *(const short8*)&wcT[col * KP + lg * 8];
                else        bfr[nt] = short8{0, 0, 0, 0, 0, 0, 0, 0};
            } else {
                #pragma unroll
                for (int j = 0; j < 8; ++j) {
                    const int k = lg * 8 + j;
                    bfr[nt][j] = (short)((k < R_OUT) ? f2bf(Wc[k * C_OUT + col]) : 0);
                }
            }
        }
        if (qt == 0) __syncthreads();

        for (int mt = 0; mt < nmt; ++mt) {
            const short8 af = *(const short8*)&s_hb[(mt * 16 + lr) * HPAD + lg * 8];
            #pragma unroll
            for (int nt = 0; nt < 4; ++nt) {
                floatx4 acc = { bcv[nt], bcv[nt], bcv[nt], bcv[nt] };
                acc = __builtin_amdgcn_mfma_f32_16x16x32_bf16(af, bfr[nt], acc, 0, 0, 0);
                pool[qt * 4 + nt] += fmaxf(acc[0], 0.f) + fmaxf(acc[1], 0.f)
                                   + fmaxf(acc[2], 0.f) + fmaxf(acc[3], 0.f);
            }
        }
        if (lg == 0) {
            #pragma unroll
            for (int nt = 0; nt < 4; ++nt)
                pool[qt * 4 + nt] -= dead * fmaxf(bcv[nt], 0.f);
        }
    }

    #pragma unroll
    for (int i = 0; i < 16; ++i) {
        float p = pool[i];
        p += __shfl_xor(p, 16);
        p += __shfl_xor(p, 32);
        pool[i] = p;
    }
    __syncthreads();
    if (lg == 0) {
        #pragma unroll
        for (int qt = 0; qt < 4; ++qt)
            #pragma unroll
            for (int nt = 0; nt < 4; ++nt)
                s_pool[wv * 256 + qt * 64 + nt * 16 + lr] = pool[qt * 4 + nt];
    }
    __syncthreads();

    {
        const int m = t & 31, part = t >> 5;
        const float4* pp = (const float4*)&s_pool[part * 128];
        const float* wrow = W1 + (size_t)(part * 128) * 32 + m;
        float s = 0.f;
        #pragma unroll
        for (int jq = 0; jq < 32; ++jq) {
            const float4 pv = pp[jq];
            s += pv.x * wrow[0] + pv.y * wrow[32] + pv.z * wrow[64] + pv.w * wrow[96];
            wrow += 128;
        }
        s_red[part * 32 + m] = s;
    }
    __syncthreads();
    if (t < 32) {
        float s = b1[t];
        #pragma unroll
        for (int p = 0; p < 8; ++p) s += s_red[p * 32 + t];
        s_d1[t] = fmaxf(s, 0.f);
    }
    __syncthreads();
    if (t < 16) {
        float s = b5[t];
        #pragma unroll
        for (int m = 0; m < 32; ++m) s += s_d1[m] * W5[m * 16 + t];
        s_d5[t] = fmaxf(s, 0.f);
    }
    __syncthreads();
    if (t == 0) {
        float mv = b6[0];
        #pragma unroll
        for (int m = 0; m < 16; ++m) mv += s_d5[m] * W6[m];
        float o = b7[0] + W7[0] * mv;
        #pragma unroll
        for (int i = 0; i < NPHYS; ++i) o += W7[i + 1] * s_phys[i];
        out[(size_t)b * 16] = o;
    }
}

extern "C" void kernel_launch(void* const* d_in, const int* in_sizes, int n_in,
                              void* d_out, int out_size, void* d_ws, size_t ws_size,
                              hipStream_t stream) {
    const float* inputs = (const float*)d_in[0];
    const int*   i_s    = (const int*)d_in[1];
    const float* W_self = (const float*)d_in[2];
    const float* W_nei  = (const float*)d_in[3];
    const float* b_r    = (const float*)d_in[4];
    const float* Wc     = (const float*)d_in[5];
    const float* bc     = (const float*)d_in[6];
    const float* W1     = (const float*)d_in[7];
    const float* b1     = (const float*)d_in[8];
    const float* W5     = (const float*)d_in[9];
    const float* b5     = (const float*)d_in[10];
    const float* W6     = (const float*)d_in[11];
    const float* b6     = (const float*)d_in[12];
    const float* W7     = (const float*)d_in[13];
    const float* b7     = (const float*)d_in[14];
    float* out = (float*)d_out;

    const int B = in_sizes[1];   // 1024
    const size_t off_wct   = 0;
    const size_t wct_b     = (size_t)C_OUT * KP * sizeof(ushort);          // 49152
    const size_t off_hnei  = off_wct + wct_b;
    const size_t hnei_b    = (size_t)B * 32 * sizeof(float);               // 131072
    const size_t off_wsf   = off_hnei + hnei_b;
    const size_t wsf_b     = (size_t)64 * 4 * 8 * sizeof(ushort);          // 4096
    const size_t off_cnt   = off_wsf + wsf_b;
    const size_t cnt_b     = (size_t)B * sizeof(int);                      // 4096
    const size_t off_pool  = off_cnt + cnt_b;
    const size_t pool_b    = (size_t)NSPL * B * 1024 * sizeof(ushort);     // 8 MiB
    const size_t need      = off_pool + pool_b;

    ushort* wcT    = (ushort*)((char*)d_ws + off_wct);
    float*  hneip  = (float*)((char*)d_ws + off_hnei);
    ushort* wsfrag = (ushort*)((char*)d_ws + off_wsf);
    int*    cnt    = (int*)((char*)d_ws + off_cnt);
    ushort* poolp  = (ushort*)((char*)d_ws + off_pool);

    if (ws_size >= need && (B % 8) == 0) {
        pggcn_prep<<<B + WCB + 1, BLOCK, 0, stream>>>(inputs, i_s, W_self, W_nei,
            b_r, Wc, hneip, wcT, wsfrag, cnt, out, B);
        pggcn_main<<<NSPL * B, BLOCK, 0, stream>>>(inputs, i_s, bc, wcT, wsfrag,
            hneip, W1, b1, W5, b5, W6, b6, W7, b7, poolp, cnt, out, B);
    } else if (ws_size >= wct_b) {
        wc_prep<<<WCB, 256, 0, stream>>>(Wc, wcT);
        pggcn_kernel<true><<<B, BLOCK, 0, stream>>>(inputs, i_s, W_self, W_nei, b_r,
            Wc, bc, W1, b1, W5, b5, W6, b6, W7, b7, wcT, out);
    } else {
        pggcn_kernel<false><<<B, BLOCK, 0, stream>>>(inputs, i_s, W_self, W_nei, b_r,
            Wc, bc, W1, b1, W5, b5, W6, b6, W7, b7, nullptr, out);
    }
}

// Round 17
// 115.997 us; speedup vs baseline: 2.7773x; 2.7773x over previous
//
#include <hip/hip_runtime.h>
#include <hip/hip_bf16.h>

#define A_DIM 200
#define F_DIM 53
#define NAF 38
#define NPHYS 15
#define R_OUT 20
#define C_OUT 1024
#define BLOCK 256
#define HPAD 40      // ushort row stride of LDS tile
#define MROWS 208
#define NSPL 4       // row splits per batch
#define KP 24        // wcT k-stride (k>=20 zeroed)
#define WCB ((C_OUT * KP + 255) / 256)

typedef __attribute__((ext_vector_type(8))) short short8;
typedef __attribute__((ext_vector_type(4))) float floatx4;

__device__ __forceinline__ float bf2f(ushort u) { return __uint_as_float((uint)u << 16); }
__device__ __forceinline__ ushort f2bf(float f) {
    union { __hip_bfloat16 h; ushort u; } cv; cv.h = __float2bfloat16(f); return cv.u;
}

// standalone wcT prep (fallback tier only)
__global__ void wc_prep(const float* __restrict__ Wc, ushort* __restrict__ wcT) {
    const int i = blockIdx.x * 256 + threadIdx.x;
    if (i >= C_OUT * KP) return;
    const int col = i / KP, k = i - col * KP;
    wcT[i] = f2bf((k < R_OUT) ? Wc[k * C_OUT + col] : 0.f);
}

// ===== A: [0,nB): agg->hnei+physics | [nB,nB+WCB): wcT | nB+WCB: wsfrag =====
__global__ __launch_bounds__(256, 8) void pggcn_prep(
    const float* __restrict__ inputs,
    const int*   __restrict__ i_s,
    const float* __restrict__ W_self,
    const float* __restrict__ W_nei,
    const float* __restrict__ b_r,
    const float* __restrict__ Wc,
    float* __restrict__ hneip,    // [B][32]
    ushort* __restrict__ wcT,     // [1024][24]
    ushort* __restrict__ wsfrag,  // [64][4] short8 = 4 KB
    float* __restrict__ out,
    int nB)
{
    __shared__ float s_aggp[4 * 56];
    __shared__ float s_agg[NAF];
    const int bx = blockIdx.x, t = threadIdx.x;

    if (bx >= nB) {
        if (bx == nB + WCB) {
            // W_self B-frag table: consumer lane l, frag q: q0/q1 = bws0[0/1],
            // q2/q3 = bws1[0/1]
            const int l = t >> 2, q = t & 3;
            const int lr = l & 15, lg = l >> 4;
            const int nt = q & 1, ks = q >> 1;
            const int c = nt * 16 + lr;
            short8 v;
            #pragma unroll
            for (int j = 0; j < 8; ++j) {
                const int k = ks * 32 + lg * 8 + j;
                const bool p = (c < R_OUT) && (k < NAF);
                v[j] = (short)(p ? f2bf(W_self[k * R_OUT + c]) : 0);
            }
            *(short8*)&wsfrag[(size_t)t * 8] = v;
            return;
        }
        const int i = (bx - nB) * 256 + t;   // wcT conversion chunk
        if (i < C_OUT * KP) {
            const int col = i / KP, k = i - col * KP;
            wcT[i] = f2bf((k < R_OUT) ? Wc[k * C_OUT + col] : 0.f);
        }
        return;
    }

    const int b = bx;
    const int ns = i_s[b];
    const float* in_b = inputs + (size_t)b * (A_DIM * F_DIM);

    if (t < NPHYS) out[(size_t)b * 16 + 1 + t] = in_b[NAF + t];

    // 4 row-groups x 53 cols, 4-deep batched loads
    if (t < 4 * F_DIM) {
        const int g = t / F_DIM, c = t - g * F_DIM;
        const float* p = in_b + g * F_DIM + c;
        float s = 0.f;
        int r = g;
        for (; r + 16 <= ns; r += 16) {
            const float v0 = p[0], v1 = p[4 * F_DIM], v2 = p[8 * F_DIM], v3 = p[12 * F_DIM];
            s += (v0 + v1) + (v2 + v3);
            p += 16 * F_DIM;
        }
        for (; r < ns; r += 4) { s += *p; p += 4 * F_DIM; }
        s_aggp[g * 56 + c] = s;
    }
    __syncthreads();
    if (t < NAF) s_agg[t] = (s_aggp[t] + s_aggp[56 + t]) + (s_aggp[112 + t] + s_aggp[168 + t]);
    __syncthreads();
    if (t < 32) {
        float s = 0.f;
        if (t < R_OUT) {
            s = b_r[t];
            #pragma unroll
            for (int f = 0; f < NAF; ++f) s += s_agg[f] * W_nei[f * R_OUT + t];
        }
        hneip[(size_t)b * 32 + t] = s;
    }
}

// frag-set load / compute macros (all indices compile-time after unroll)
#define LOADF(F, C, QT) do {                                                  \
    _Pragma("unroll")                                                         \
    for (int nt = 0; nt < 4; ++nt) {                                          \
        const int col = wv * 256 + (QT) * 64 + nt * 16 + lr;                  \
        C[nt] = bc[col];                                                      \
        if (lg < 3) F[nt] = *(const short8*)&wcT[col * KP + lg * 8];          \
        else        F[nt] = short8{0, 0, 0, 0, 0, 0, 0, 0};                   \
    } } while (0)

#define COMPUTEQ(F, C, QT) do {                                               \
    for (int mt = 0; mt < ntl; ++mt) {                                        \
        const short8 af = *(const short8*)&s_hb[(mt * 16 + lr) * HPAD + lg * 8]; \
        _Pragma("unroll")                                                     \
        for (int nt = 0; nt < 4; ++nt) {                                      \
            floatx4 acc = { C[nt], C[nt], C[nt], C[nt] };                     \
            acc = __builtin_amdgcn_mfma_f32_16x16x32_bf16(af, F[nt], acc, 0, 0, 0); \
            pool[(QT) * 4 + nt] += fmaxf(acc[0], 0.f) + fmaxf(acc[1], 0.f)    \
                                 + fmaxf(acc[2], 0.f) + fmaxf(acc[3], 0.f);   \
        }                                                                     \
    }                                                                         \
    if (lg == 0) {                                                            \
        _Pragma("unroll")                                                     \
        for (int nt = 0; nt < 4; ++nt)                                        \
            pool[(QT) * 4 + nt] -= dead * fmaxf(C[nt], 0.f);                  \
    } } while (0)

// ===== B: row-quarter blocks -> partial pooled (bf16) to pooledp[split][b][1024] =====
__global__ __launch_bounds__(256, 8) void pggcn_main(
    const float* __restrict__ inputs,
    const int*   __restrict__ i_s,
    const float* __restrict__ bc,
    const ushort* __restrict__ wcT,
    const ushort* __restrict__ wsfrag,
    const float* __restrict__ hneip,
    ushort* __restrict__ pooledp,
    int nB)
{
    __shared__ __align__(16) ushort s_hb[64 * HPAD];   // 5120 B (atoms -> h in place)
    float* s_pool = (float*)s_hb;                      // 1024 f alias (post-main)

    const int bx    = blockIdx.x;
    const int split = bx / nB;           // 0..3 (split-major keeps batch on one XCD)
    const int b     = bx - split * nB;
    const int t     = threadIdx.x;
    const int lane  = t & 63;
    const int wv    = t >> 6;
    const int lr    = lane & 15;
    const int lg    = lane >> 4;
    const int ns    = i_s[b];
    const int nmt   = (ns + 15) >> 4;
    const int lt0   = (nmt * split) >> 2;
    const int lt1   = (nmt * (split + 1)) >> 2;
    const int ntl   = lt1 - lt0;         // 0..4 tiles
    ushort* outp = pooledp + ((size_t)(split * nB + b)) * 1024;

    if (ntl <= 0) {   // no rows: publish exact zeros (block-uniform, no barriers)
        ushort4 z = {0, 0, 0, 0};
        ((ushort4*)outp)[t] = z;
        return;
    }
    const int row0  = lt0 * 16;
    const int nrows = ntl * 16;
    const float* in_b = inputs + (size_t)b * (A_DIM * F_DIM);

    const float hn0 = hneip[(size_t)b * 32 + lr];
    const float hn1 = hneip[(size_t)b * 32 + 16 + lr];

    // W_self B-frags: 4 coalesced 16B loads from the precomputed table
    const short8 bws00 = *(const short8*)&wsfrag[(size_t)(lane * 4 + 0) * 8];
    const short8 bws01 = *(const short8*)&wsfrag[(size_t)(lane * 4 + 1) * 8];
    const short8 bws10 = *(const short8*)&wsfrag[(size_t)(lane * 4 + 2) * 8];
    const short8 bws11 = *(const short8*)&wsfrag[(size_t)(lane * 4 + 3) * 8];

    // ---- stage valid rows bf16, thread-per-row-quad: r = t>>2, f = (t&3)*10..+9 ----
    const int vloc = (ns - row0 < nrows) ? (ns - row0) : nrows;
    {
        const int r = t >> 2, q = t & 3;
        if (r < vloc) {
            const float* rp = in_b + (size_t)(row0 + r) * F_DIM + q * 10;
            uint* dst = (uint*)&s_hb[r * HPAD + q * 10];
            #pragma unroll
            for (int p = 0; p < 5; ++p) {
                const uint lo = f2bf(rp[2 * p]);
                const uint hi = f2bf(rp[2 * p + 1]);
                dst[p] = lo | (hi << 16);
            }
        }
    }
    __syncthreads();

    // ---- h-MFMA in place: h = (row valid) ? relu(atom@W_self + hnei) : 0 ----
    for (int lt = wv; lt < ntl; lt += 4) {
        const int ar = lt * 16 + lr;
        const short8 a0 = *(const short8*)&s_hb[ar * HPAD + lg * 8];
        short8 a1 = short8{0, 0, 0, 0, 0, 0, 0, 0};
        if (lg == 0) a1 = *(const short8*)&s_hb[ar * HPAD + 32];
        floatx4 aS0 = {hn0, hn0, hn0, hn0};
        floatx4 aS1 = {hn1, hn1, hn1, hn1};
        aS0 = __builtin_amdgcn_mfma_f32_16x16x32_bf16(a0, bws00, aS0, 0, 0, 0);
        aS0 = __builtin_amdgcn_mfma_f32_16x16x32_bf16(a1, bws10, aS0, 0, 0, 0);
        aS1 = __builtin_amdgcn_mfma_f32_16x16x32_bf16(a0, bws01, aS1, 0, 0, 0);
        aS1 = __builtin_amdgcn_mfma_f32_16x16x32_bf16(a1, bws11, aS1, 0, 0, 0);
        // C/D: col = lane&15, row = (lane>>4)*4 + q
        #pragma unroll
        for (int q = 0; q < 4; ++q) {
            const int lrow = lt * 16 + lg * 4 + q;
            const bool vv = lrow < vloc;
            s_hb[lrow * HPAD + lr]      = vv ? f2bf(fmaxf(aS0[q], 0.f)) : (ushort)0;
            s_hb[lrow * HPAD + 16 + lr] = vv ? f2bf(fmaxf(aS1[q], 0.f)) : (ushort)0;
        }
    }

    // ---- main: 4 rounds, 1-deep software pipeline (two alternating frag sets) ----
    const float dead = (float)(nrows - vloc);
    float pool[16];
    #pragma unroll
    for (int i = 0; i < 16; ++i) pool[i] = 0.f;

    short8 fA[4], fB[4];
    float  cA[4], cB[4];
    LOADF(fA, cA, 0);          // round-0 loads fly while waiting at the barrier
    __syncthreads();           // h ready
    LOADF(fB, cB, 1);          // issue round-1 loads, then compute round 0
    COMPUTEQ(fA, cA, 0);
    LOADF(fA, cA, 2);
    COMPUTEQ(fB, cB, 1);
    LOADF(fB, cB, 3);
    COMPUTEQ(fA, cA, 2);
    COMPUTEQ(fB, cB, 3);

    #pragma unroll
    for (int i = 0; i < 16; ++i) {
        float p = pool[i];
        p += __shfl_xor(p, 16);
        p += __shfl_xor(p, 32);
        pool[i] = p;
    }
    __syncthreads();   // all s_hb reads done; alias safe
    if (lg == 0) {
        #pragma unroll
        for (int qt = 0; qt < 4; ++qt)
            #pragma unroll
            for (int nt = 0; nt < 4; ++nt)
                s_pool[wv * 256 + qt * 64 + nt * 16 + lr] = pool[qt * 4 + nt];
    }
    __syncthreads();

    // ---- pack bf16 + one coalesced store ----
    {
        const float4 pv = ((const float4*)s_pool)[t];
        ushort4 o;
        o.x = f2bf(pv.x); o.y = f2bf(pv.y); o.z = f2bf(pv.z); o.w = f2bf(pv.w);
        ((ushort4*)outp)[t] = o;
    }
}

// ===== C: tail — 2 batches/block: pooled = sum of 4 splits; d1; d5; out0 =====
__global__ __launch_bounds__(256, 4) void pggcn_tail(
    const float* __restrict__ inputs,
    const ushort* __restrict__ pooledp,
    const float* __restrict__ W1,
    const float* __restrict__ b1,
    const float* __restrict__ W5,
    const float* __restrict__ b5,
    const float* __restrict__ W6,
    const float* __restrict__ b6,
    const float* __restrict__ W7,
    const float* __restrict__ b7,
    float* __restrict__ out, int nB)
{
    __shared__ float s_pool2[2][1024];   // 8 KB
    __shared__ float s_red[8 * 2 * 32];  // 2 KB
    __shared__ float s_d1[2 * 32];
    const int t = threadIdx.x;
    const int b0 = blockIdx.x * 2;

    // sum the 4 split partials (bf16 -> fp32)
    #pragma unroll
    for (int g = 0; g < 2; ++g) {
        const uint* q0 = (const uint*)(pooledp + (size_t)(0 * nB + b0 + g) * 1024);
        const uint* q1 = (const uint*)(pooledp + (size_t)(1 * nB + b0 + g) * 1024);
        const uint* q2 = (const uint*)(pooledp + (size_t)(2 * nB + b0 + g) * 1024);
        const uint* q3 = (const uint*)(pooledp + (size_t)(3 * nB + b0 + g) * 1024);
        for (int i = t; i < 512; i += 256) {
            const uint u0 = q0[i], u1 = q1[i], u2 = q2[i], u3 = q3[i];
            s_pool2[g][2 * i] = (bf2f((ushort)u0) + bf2f((ushort)u1))
                              + (bf2f((ushort)u2) + bf2f((ushort)u3));
            s_pool2[g][2 * i + 1] = (bf2f((ushort)(u0 >> 16)) + bf2f((ushort)(u1 >> 16)))
                                  + (bf2f((ushort)(u2 >> 16)) + bf2f((ushort)(u3 >> 16)));
        }
    }
    __syncthreads();

    // d1 partials: thread (m, part of 8) accumulates 2 batches at once
    {
        const int m = t & 31, part = t >> 5;
        float acc0 = 0.f, acc1 = 0.f;
        const float* w = W1 + (size_t)(part * 128) * 32 + m;
        const int j0 = part * 128;
        for (int j = 0; j < 128; ++j) {
            const float wv_ = w[(size_t)j * 32];
            acc0 += s_pool2[0][j0 + j] * wv_;
            acc1 += s_pool2[1][j0 + j] * wv_;
        }
        s_red[(part * 2 + 0) * 32 + m] = acc0;
        s_red[(part * 2 + 1) * 32 + m] = acc1;
    }
    __syncthreads();
    if (t < 64) {
        const int g = t >> 5, m = t & 31;
        float s = b1[m];
        #pragma unroll
        for (int p = 0; p < 8; ++p) s += s_red[(p * 2 + g) * 32 + m];
        s_d1[g * 32 + m] = fmaxf(s, 0.f);
    }
    __syncthreads();
    if (t < 32) {
        const int g = t >> 4, dim = t & 15;
        float s = b5[dim];
        #pragma unroll
        for (int m = 0; m < 32; ++m) s += s_d1[g * 32 + m] * W5[m * 16 + dim];
        float c = fmaxf(s, 0.f) * W6[dim];
        c += __shfl_xor(c, 1);
        c += __shfl_xor(c, 2);
        c += __shfl_xor(c, 4);
        c += __shfl_xor(c, 8);
        if (dim == 0) {
            const int b = b0 + g;
            float o = b7[0] + W7[0] * (b6[0] + c);
            const float* ph = inputs + (size_t)b * (A_DIM * F_DIM) + NAF;
            #pragma unroll
            for (int i = 0; i < NPHYS; ++i) o += W7[i + 1] * ph[i];
            out[(size_t)b * 16] = o;
        }
    }
}

// ===== fallback (R11-proven single-kernel pipeline) =====
template <bool USE_WS>
__global__ __launch_bounds__(BLOCK, 4) void pggcn_kernel(
    const float* __restrict__ inputs,
    const int*   __restrict__ i_s,
    const float* __restrict__ W_self,
    const float* __restrict__ W_nei,
    const float* __restrict__ b_r,
    const float* __restrict__ Wc,
    const float* __restrict__ bc,
    const float* __restrict__ W1,
    const float* __restrict__ b1,
    const float* __restrict__ W5,
    const float* __restrict__ b5,
    const float* __restrict__ W6,
    const float* __restrict__ b6,
    const float* __restrict__ W7,
    const float* __restrict__ b7,
    const ushort* __restrict__ wcT,
    float* __restrict__ out)
{
    __shared__ __align__(16) ushort s_hb[MROWS * HPAD];
    __shared__ float s_aggp[6 * 40];
    __shared__ float s_agg[40];
    __shared__ float s_hnei[32];
    __shared__ float s_phys[NPHYS];

    float* s_pool = (float*)s_hb;
    float* s_red  = (float*)s_hb + 1024;
    float* s_d1   = s_red + 256;
    float* s_d5   = s_d1 + 32;

    const int b    = blockIdx.x;
    const int t    = threadIdx.x;
    const int lane = t & 63;
    const int wv   = t >> 6;
    const int lr   = lane & 15;
    const int lg   = lane >> 4;
    const int ns   = i_s[b];
    const int nmt  = (ns + 15) >> 4;
    const float* in_b = inputs + (size_t)b * (A_DIM * F_DIM);

    short8 bws0[2], bws1[2];
    #pragma unroll
    for (int nt = 0; nt < 2; ++nt) {
        const int c = nt * 16 + lr;
        const bool cv_ = (c < R_OUT);
        #pragma unroll
        for (int j = 0; j < 8; ++j) {
            const int k0 = lg * 8 + j;
            const int k1 = 32 + lg * 8 + j;
            bws0[nt][j] = (short)(cv_ ? f2bf(W_self[k0 * R_OUT + c]) : 0);
            bws1[nt][j] = (short)((cv_ && k1 < NAF) ? f2bf(W_self[k1 * R_OUT + c]) : 0);
        }
    }

    if (t < NPHYS) {
        const float p = in_b[NAF + t];
        s_phys[t] = p;
        out[(size_t)b * 16 + 1 + t] = p;
    }

    const int tot = nmt * 16 * HPAD;
    for (int i = t; i < tot; i += BLOCK) {
        const int r = i / HPAD;
        const int f = i - r * HPAD;
        const float v = (r < ns && f < NAF) ? in_b[r * F_DIM + f] : 0.f;
        s_hb[i] = f2bf(v);
    }
    __syncthreads();

    if (t < 240) {
        const int f = t % 40, g = t / 40;
        float s = 0.f;
        for (int r = g; r < ns; r += 6) s += bf2f(s_hb[r * HPAD + f]);
        s_aggp[g * 40 + f] = s;
    }
    __syncthreads();
    if (t < 40) {
        float s = 0.f;
        #pragma unroll
        for (int g = 0; g < 6; ++g) s += s_aggp[g * 40 + t];
        s_agg[t] = s;
    }
    __syncthreads();
    if (t < 32) {
        float s = 0.f;
        if (t < R_OUT) {
            s = b_r[t];
            #pragma unroll
            for (int f = 0; f < NAF; ++f) s += s_agg[f] * W_nei[f * R_OUT + t];
        }
        s_hnei[t] = s;
    }
    __syncthreads();

    for (int mt = wv; mt < nmt; mt += 4) {
        const int ar = mt * 16 + lr;
        const short8 a0 = *(const short8*)&s_hb[ar * HPAD + lg * 8];
        short8 a1 = short8{0, 0, 0, 0, 0, 0, 0, 0};
        if (lg == 0) a1 = *(const short8*)&s_hb[ar * HPAD + 32];
        const float hn0 = s_hnei[lr];
        const float hn1 = s_hnei[16 + lr];
        floatx4 aS0 = {hn0, hn0, hn0, hn0};
        floatx4 aS1 = {hn1, hn1, hn1, hn1};
        aS0 = __builtin_amdgcn_mfma_f32_16x16x32_bf16(a0, bws0[0], aS0, 0, 0, 0);
        aS0 = __builtin_amdgcn_mfma_f32_16x16x32_bf16(a1, bws1[0], aS0, 0, 0, 0);
        aS1 = __builtin_amdgcn_mfma_f32_16x16x32_bf16(a0, bws0[1], aS1, 0, 0, 0);
        aS1 = __builtin_amdgcn_mfma_f32_16x16x32_bf16(a1, bws1[1], aS1, 0, 0, 0);
        #pragma unroll
        for (int q = 0; q < 4; ++q) {
            const int row = mt * 16 + lg * 4 + q;
            const bool v = (row < ns);
            s_hb[row * HPAD + lr]      = v ? f2bf(fmaxf(aS0[q], 0.f)) : (ushort)0;
            s_hb[row * HPAD + 16 + lr] = v ? f2bf(fmaxf(aS1[q], 0.f)) : (ushort)0;
        }
    }

    const float dead = (float)(nmt * 16 - ns);
    float pool[16];
    #pragma unroll
    for (int i = 0; i < 16; ++i) pool[i] = 0.f;

    #pragma unroll 1
    for (int qt = 0; qt < 4; ++qt) {
        short8 bfr[4];
        float  bcv[4];
        #pragma unroll
        for (int nt = 0; nt < 4; ++nt) {
            const int col = wv * 256 + qt * 64 + nt * 16 + lr;
            bcv[nt] = bc[col];
            if (USE_WS) {
                if (lg < 3) bfr[nt] = *(const short8*)&wcT[col * KP + lg * 8];
                else        bfr[nt] = short8{0, 0, 0, 0, 0, 0, 0, 0};
            } else {
                #pragma unroll
                for (int j = 0; j < 8; ++j) {
                    const int k = lg * 8 + j;
                    bfr[nt][j] = (short)((k < R_OUT) ? f2bf(Wc[k * C_OUT + col]) : 0);
                }
            }
        }
        if (qt == 0) __syncthreads();

        for (int mt = 0; mt < nmt; ++mt) {
            const short8 af = *(const short8*)&s_hb[(mt * 16 + lr) * HPAD + lg * 8];
            #pragma unroll
            for (int nt = 0; nt < 4; ++nt) {
                floatx4 acc = { bcv[nt], bcv[nt], bcv[nt], bcv[nt] };
                acc = __builtin_amdgcn_mfma_f32_16x16x32_bf16(af, bfr[nt], acc, 0, 0, 0);
                pool[qt * 4 + nt] += fmaxf(acc[0], 0.f) + fmaxf(acc[1], 0.f)
                                   + fmaxf(acc[2], 0.f) + fmaxf(acc[3], 0.f);
            }
        }
        if (lg == 0) {
            #pragma unroll
            for (int nt = 0; nt < 4; ++nt)
                pool[qt * 4 + nt] -= dead * fmaxf(bcv[nt], 0.f);
        }
    }

    #pragma unroll
    for (int i = 0; i < 16; ++i) {
        float p = pool[i];
        p += __shfl_xor(p, 16);
        p += __shfl_xor(p, 32);
        pool[i] = p;
    }
    __syncthreads();
    if (lg == 0) {
        #pragma unroll
        for (int qt = 0; qt < 4; ++qt)
            #pragma unroll
            for (int nt = 0; nt < 4; ++nt)
                s_pool[wv * 256 + qt * 64 + nt * 16 + lr] = pool[qt * 4 + nt];
    }
    __syncthreads();

    {
        const int m = t & 31, part = t >> 5;
        const float4* pp = (const float4*)&s_pool[part * 128];
        const float* wrow = W1 + (size_t)(part * 128) * 32 + m;
        float s = 0.f;
        #pragma unroll
        for (int jq = 0; jq < 32; ++jq) {
            const float4 pv = pp[jq];
            s += pv.x * wrow[0] + pv.y * wrow[32] + pv.z * wrow[64] + pv.w * wrow[96];
            wrow += 128;
        }
        s_red[part * 32 + m] = s;
    }
    __syncthreads();
    if (t < 32) {
        float s = b1[t];
        #pragma unroll
        for (int p = 0; p < 8; ++p) s += s_red[p * 32 + t];
        s_d1[t] = fmaxf(s, 0.f);
    }
    __syncthreads();
    if (t < 16) {
        float s = b5[t];
        #pragma unroll
        for (int m = 0; m < 32; ++m) s += s_d1[m] * W5[m * 16 + t];
        s_d5[t] = fmaxf(s, 0.f);
    }
    __syncthreads();
    if (t == 0) {
        float mv = b6[0];
        #pragma unroll
        for (int m = 0; m < 16; ++m) mv += s_d5[m] * W6[m];
        float o = b7[0] + W7[0] * mv;
        #pragma unroll
        for (int i = 0; i < NPHYS; ++i) o += W7[i + 1] * s_phys[i];
        out[(size_t)b * 16] = o;
    }
}

extern "C" void kernel_launch(void* const* d_in, const int* in_sizes, int n_in,
                              void* d_out, int out_size, void* d_ws, size_t ws_size,
                              hipStream_t stream) {
    const float* inputs = (const float*)d_in[0];
    const int*   i_s    = (const int*)d_in[1];
    const float* W_self = (const float*)d_in[2];
    const float* W_nei  = (const float*)d_in[3];
    const float* b_r    = (const float*)d_in[4];
    const float* Wc     = (const float*)d_in[5];
    const float* bc     = (const float*)d_in[6];
    const float* W1     = (const float*)d_in[7];
    const float* b1     = (const float*)d_in[8];
    const float* W5     = (const float*)d_in[9];
    const float* b5     = (const float*)d_in[10];
    const float* W6     = (const float*)d_in[11];
    const float* b6     = (const float*)d_in[12];
    const float* W7     = (const float*)d_in[13];
    const float* b7     = (const float*)d_in[14];
    float* out = (float*)d_out;

    const int B = in_sizes[1];   // 1024
    const size_t off_wct   = 0;
    const size_t wct_b     = (size_t)C_OUT * KP * sizeof(ushort);          // 49152
    const size_t off_hnei  = off_wct + wct_b;
    const size_t hnei_b    = (size_t)B * 32 * sizeof(float);               // 131072
    const size_t off_wsf   = off_hnei + hnei_b;
    const size_t wsf_b     = (size_t)64 * 4 * 8 * sizeof(ushort);          // 4096
    const size_t off_pool  = off_wsf + wsf_b;
    const size_t pool_b    = (size_t)NSPL * B * 1024 * sizeof(ushort);     // 8 MiB
    const size_t need      = off_pool + pool_b;

    ushort* wcT    = (ushort*)((char*)d_ws + off_wct);
    float*  hneip  = (float*)((char*)d_ws + off_hnei);
    ushort* wsfrag = (ushort*)((char*)d_ws + off_wsf);
    ushort* poolp  = (ushort*)((char*)d_ws + off_pool);

    if (ws_size >= need && (B % 8) == 0) {
        pggcn_prep<<<B + WCB + 1, BLOCK, 0, stream>>>(inputs, i_s, W_self, W_nei,
            b_r, Wc, hneip, wcT, wsfrag, out, B);
        pggcn_main<<<NSPL * B, BLOCK, 0, stream>>>(inputs, i_s, bc, wcT, wsfrag,
                                                   hneip, poolp, B);
        pggcn_tail<<<B / 2, BLOCK, 0, stream>>>(inputs, poolp, W1, b1, W5, b5,
                                                W6, b6, W7, b7, out, B);
    } else if (ws_size >= wct_b) {
        wc_prep<<<WCB, 256, 0, stream>>>(Wc, wcT);
        pggcn_kernel<true><<<B, BLOCK, 0, stream>>>(inputs, i_s, W_self, W_nei, b_r,
            Wc, bc, W1, b1, W5, b5, W6, b6, W7, b7, wcT, out);
    } else {
        pggcn_kernel<false><<<B, BLOCK, 0, stream>>>(inputs, i_s, W_self, W_nei, b_r,
            Wc, bc, W1, b1, W5, b5, W6, b6, W7, b7, nullptr, out);
    }
}

// Round 18
// 50.066 us; speedup vs baseline: 6.4347x; 2.3169x over previous
//
#include <hip/hip_runtime.h>
#include <hip/hip_bf16.h>

#define A_DIM 200
#define F_DIM 53
#define NAF 38
#define NPHYS 15
#define R_OUT 20
#define C_OUT 1024
#define BLOCK 256
#define HPAD 40      // ushort row stride of LDS tile
#define MROWS 208
#define NSPL 4       // row splits per batch
#define KP 24        // wcT k-stride (k>=20 zeroed)
#define WCB ((C_OUT * KP + 255) / 256)

typedef __attribute__((ext_vector_type(8))) short short8;
typedef __attribute__((ext_vector_type(4))) float floatx4;

__device__ __forceinline__ float bf2f(ushort u) { return __uint_as_float((uint)u << 16); }
__device__ __forceinline__ ushort f2bf(float f) {
    union { __hip_bfloat16 h; ushort u; } cv; cv.h = __float2bfloat16(f); return cv.u;
}

// standalone wcT prep (fallback tier only)
__global__ void wc_prep(const float* __restrict__ Wc, ushort* __restrict__ wcT) {
    const int i = blockIdx.x * 256 + threadIdx.x;
    if (i >= C_OUT * KP) return;
    const int col = i / KP, k = i - col * KP;
    wcT[i] = f2bf((k < R_OUT) ? Wc[k * C_OUT + col] : 0.f);
}

// ===== A: [0,nB): agg->hnei+physics | [nB,nB+WCB): wcT | nB+WCB: wsfrag =====
__global__ __launch_bounds__(256, 8) void pggcn_prep(
    const float* __restrict__ inputs,
    const int*   __restrict__ i_s,
    const float* __restrict__ W_self,
    const float* __restrict__ W_nei,
    const float* __restrict__ b_r,
    const float* __restrict__ Wc,
    float* __restrict__ hneip,    // [B][32]
    ushort* __restrict__ wcT,     // [1024][24]
    ushort* __restrict__ wsfrag,  // [64][4] short8 = 4 KB
    float* __restrict__ out,
    int nB)
{
    __shared__ float s_aggp[4 * 56];
    __shared__ float s_agg[NAF];
    const int bx = blockIdx.x, t = threadIdx.x;

    if (bx >= nB) {
        if (bx == nB + WCB) {
            // W_self B-frag table: consumer lane l, frag q: q0/q1 = bws0[0/1],
            // q2/q3 = bws1[0/1]
            const int l = t >> 2, q = t & 3;
            const int lr = l & 15, lg = l >> 4;
            const int nt = q & 1, ks = q >> 1;
            const int c = nt * 16 + lr;
            short8 v;
            #pragma unroll
            for (int j = 0; j < 8; ++j) {
                const int k = ks * 32 + lg * 8 + j;
                const bool p = (c < R_OUT) && (k < NAF);
                v[j] = (short)(p ? f2bf(W_self[k * R_OUT + c]) : 0);
            }
            *(short8*)&wsfrag[(size_t)t * 8] = v;
            return;
        }
        const int i = (bx - nB) * 256 + t;   // wcT conversion chunk
        if (i < C_OUT * KP) {
            const int col = i / KP, k = i - col * KP;
            wcT[i] = f2bf((k < R_OUT) ? Wc[k * C_OUT + col] : 0.f);
        }
        return;
    }

    const int b = bx;
    const int ns = i_s[b];
    const float* in_b = inputs + (size_t)b * (A_DIM * F_DIM);

    if (t < NPHYS) out[(size_t)b * 16 + 1 + t] = in_b[NAF + t];

    // 4 row-groups x 53 cols, 4-deep batched loads
    if (t < 4 * F_DIM) {
        const int g = t / F_DIM, c = t - g * F_DIM;
        const float* p = in_b + g * F_DIM + c;
        float s = 0.f;
        int r = g;
        for (; r + 16 <= ns; r += 16) {
            const float v0 = p[0], v1 = p[4 * F_DIM], v2 = p[8 * F_DIM], v3 = p[12 * F_DIM];
            s += (v0 + v1) + (v2 + v3);
            p += 16 * F_DIM;
        }
        for (; r < ns; r += 4) { s += *p; p += 4 * F_DIM; }
        s_aggp[g * 56 + c] = s;
    }
    __syncthreads();
    if (t < NAF) s_agg[t] = (s_aggp[t] + s_aggp[56 + t]) + (s_aggp[112 + t] + s_aggp[168 + t]);
    __syncthreads();
    if (t < 32) {
        float s = 0.f;
        if (t < R_OUT) {
            s = b_r[t];
            #pragma unroll
            for (int f = 0; f < NAF; ++f) s += s_agg[f] * W_nei[f * R_OUT + t];
        }
        hneip[(size_t)b * 32 + t] = s;
    }
}

// ===== B: row-quarter blocks -> partial pooled (bf16) to pooledp[split][b][1024]
//       (byte-identical to R15's proven 48.3 µs main) =====
__global__ __launch_bounds__(256, 8) void pggcn_main(
    const float* __restrict__ inputs,
    const int*   __restrict__ i_s,
    const float* __restrict__ bc,
    const ushort* __restrict__ wcT,
    const ushort* __restrict__ wsfrag,
    const float* __restrict__ hneip,
    ushort* __restrict__ pooledp,
    int nB)
{
    __shared__ __align__(16) ushort s_hb[64 * HPAD];   // 5120 B (atoms -> h in place)
    float* s_pool = (float*)s_hb;                      // 1024 f alias (post-main)

    const int bx    = blockIdx.x;
    const int split = bx / nB;           // 0..3 (split-major keeps batch on one XCD)
    const int b     = bx - split * nB;
    const int t     = threadIdx.x;
    const int lane  = t & 63;
    const int wv    = t >> 6;
    const int lr    = lane & 15;
    const int lg    = lane >> 4;
    const int ns    = i_s[b];
    const int nmt   = (ns + 15) >> 4;
    const int lt0   = (nmt * split) >> 2;
    const int lt1   = (nmt * (split + 1)) >> 2;
    const int ntl   = lt1 - lt0;         // 0..4 tiles
    ushort* outp = pooledp + ((size_t)(split * nB + b)) * 1024;

    if (ntl <= 0) {   // no rows: publish exact zeros (block-uniform, no barriers)
        ushort4 z = {0, 0, 0, 0};
        ((ushort4*)outp)[t] = z;
        return;
    }
    const int row0  = lt0 * 16;
    const int nrows = ntl * 16;
    const float* in_b = inputs + (size_t)b * (A_DIM * F_DIM);

    const float hn0 = hneip[(size_t)b * 32 + lr];
    const float hn1 = hneip[(size_t)b * 32 + 16 + lr];

    // W_self B-frags: 4 coalesced 16B loads from the precomputed table
    const short8 bws00 = *(const short8*)&wsfrag[(size_t)(lane * 4 + 0) * 8];
    const short8 bws01 = *(const short8*)&wsfrag[(size_t)(lane * 4 + 1) * 8];
    const short8 bws10 = *(const short8*)&wsfrag[(size_t)(lane * 4 + 2) * 8];
    const short8 bws11 = *(const short8*)&wsfrag[(size_t)(lane * 4 + 3) * 8];

    // ---- stage valid rows bf16, thread-per-row-quad: r = t>>2, f = (t&3)*10..+9 ----
    const int vloc = (ns - row0 < nrows) ? (ns - row0) : nrows;
    {
        const int r = t >> 2, q = t & 3;
        if (r < vloc) {
            const float* rp = in_b + (size_t)(row0 + r) * F_DIM + q * 10;
            uint* dst = (uint*)&s_hb[r * HPAD + q * 10];
            #pragma unroll
            for (int p = 0; p < 5; ++p) {
                const uint lo = f2bf(rp[2 * p]);
                const uint hi = f2bf(rp[2 * p + 1]);
                dst[p] = lo | (hi << 16);
            }
        }
    }
    __syncthreads();

    // ---- h-MFMA in place: h = (row valid) ? relu(atom@W_self + hnei) : 0 ----
    for (int lt = wv; lt < ntl; lt += 4) {
        const int ar = lt * 16 + lr;
        const short8 a0 = *(const short8*)&s_hb[ar * HPAD + lg * 8];
        short8 a1 = short8{0, 0, 0, 0, 0, 0, 0, 0};
        if (lg == 0) a1 = *(const short8*)&s_hb[ar * HPAD + 32];
        floatx4 aS0 = {hn0, hn0, hn0, hn0};
        floatx4 aS1 = {hn1, hn1, hn1, hn1};
        aS0 = __builtin_amdgcn_mfma_f32_16x16x32_bf16(a0, bws00, aS0, 0, 0, 0);
        aS0 = __builtin_amdgcn_mfma_f32_16x16x32_bf16(a1, bws10, aS0, 0, 0, 0);
        aS1 = __builtin_amdgcn_mfma_f32_16x16x32_bf16(a0, bws01, aS1, 0, 0, 0);
        aS1 = __builtin_amdgcn_mfma_f32_16x16x32_bf16(a1, bws11, aS1, 0, 0, 0);
        // C/D: col = lane&15, row = (lane>>4)*4 + q
        #pragma unroll
        for (int q = 0; q < 4; ++q) {
            const int lrow = lt * 16 + lg * 4 + q;
            const bool vv = lrow < vloc;
            s_hb[lrow * HPAD + lr]      = vv ? f2bf(fmaxf(aS0[q], 0.f)) : (ushort)0;
            s_hb[lrow * HPAD + 16 + lr] = vv ? f2bf(fmaxf(aS1[q], 0.f)) : (ushort)0;
        }
    }

    // ---- main: partial pooled over own rows, all 1024 cols (4 rounds x 4) ----
    const float dead = (float)(nrows - vloc);
    float pool[16];
    #pragma unroll
    for (int i = 0; i < 16; ++i) pool[i] = 0.f;

    #pragma unroll 1
    for (int qt = 0; qt < 4; ++qt) {
        short8 bfr[4];
        float  bcv[4];
        #pragma unroll
        for (int nt = 0; nt < 4; ++nt) {
            const int col = wv * 256 + qt * 64 + nt * 16 + lr;
            bcv[nt] = bc[col];
            if (lg < 3) bfr[nt] = *(const short8*)&wcT[col * KP + lg * 8];
            else        bfr[nt] = short8{0, 0, 0, 0, 0, 0, 0, 0};
        }
        if (qt == 0) __syncthreads();   // h ready; frag-load latency overlapped

        for (int mt = 0; mt < ntl; ++mt) {
            const short8 af = *(const short8*)&s_hb[(mt * 16 + lr) * HPAD + lg * 8];
            #pragma unroll
            for (int nt = 0; nt < 4; ++nt) {
                floatx4 acc = { bcv[nt], bcv[nt], bcv[nt], bcv[nt] };
                acc = __builtin_amdgcn_mfma_f32_16x16x32_bf16(af, bfr[nt], acc, 0, 0, 0);
                pool[qt * 4 + nt] += fmaxf(acc[0], 0.f) + fmaxf(acc[1], 0.f)
                                   + fmaxf(acc[2], 0.f) + fmaxf(acc[3], 0.f);
            }
        }
        if (lg == 0) {   // local dead rows contributed relu(bc) each
            #pragma unroll
            for (int nt = 0; nt < 4; ++nt)
                pool[qt * 4 + nt] -= dead * fmaxf(bcv[nt], 0.f);
        }
    }
    #pragma unroll
    for (int i = 0; i < 16; ++i) {
        float p = pool[i];
        p += __shfl_xor(p, 16);
        p += __shfl_xor(p, 32);
        pool[i] = p;
    }
    __syncthreads();   // all s_hb reads done; alias safe
    if (lg == 0) {
        #pragma unroll
        for (int qt = 0; qt < 4; ++qt)
            #pragma unroll
            for (int nt = 0; nt < 4; ++nt)
                s_pool[wv * 256 + qt * 64 + nt * 16 + lr] = pool[qt * 4 + nt];
    }
    __syncthreads();

    // ---- pack bf16 + one coalesced store ----
    {
        const float4 pv = ((const float4*)s_pool)[t];
        ushort4 o;
        o.x = f2bf(pv.x); o.y = f2bf(pv.y); o.z = f2bf(pv.z); o.w = f2bf(pv.w);
        ((ushort4*)outp)[t] = o;
    }
}

// ===== C: tail — 4 batches/block: pooled = sum of 4 splits; d1; d5; out0 =====
__global__ __launch_bounds__(256, 4) void pggcn_tail(
    const float* __restrict__ inputs,
    const ushort* __restrict__ pooledp,
    const float* __restrict__ W1,
    const float* __restrict__ b1,
    const float* __restrict__ W5,
    const float* __restrict__ b5,
    const float* __restrict__ W6,
    const float* __restrict__ b6,
    const float* __restrict__ W7,
    const float* __restrict__ b7,
    float* __restrict__ out, int nB)
{
    __shared__ float s_pool2[4][1024];   // 16 KB
    __shared__ float s_red[8 * 4 * 32];  // 4 KB
    __shared__ float s_d1[4 * 32];
    const int t = threadIdx.x;
    const int b0 = blockIdx.x * 4;

    // sum the 4 split partials (bf16 -> fp32)
    #pragma unroll
    for (int g = 0; g < 4; ++g) {
        const uint* q0 = (const uint*)(pooledp + (size_t)(0 * nB + b0 + g) * 1024);
        const uint* q1 = (const uint*)(pooledp + (size_t)(1 * nB + b0 + g) * 1024);
        const uint* q2 = (const uint*)(pooledp + (size_t)(2 * nB + b0 + g) * 1024);
        const uint* q3 = (const uint*)(pooledp + (size_t)(3 * nB + b0 + g) * 1024);
        for (int i = t; i < 512; i += 256) {
            const uint u0 = q0[i], u1 = q1[i], u2 = q2[i], u3 = q3[i];
            s_pool2[g][2 * i] = (bf2f((ushort)u0) + bf2f((ushort)u1))
                              + (bf2f((ushort)u2) + bf2f((ushort)u3));
            s_pool2[g][2 * i + 1] = (bf2f((ushort)(u0 >> 16)) + bf2f((ushort)(u1 >> 16)))
                                  + (bf2f((ushort)(u2 >> 16)) + bf2f((ushort)(u3 >> 16)));
        }
    }
    __syncthreads();

    // d1 partials: thread (m, part of 8) accumulates 4 batches at once
    {
        const int m = t & 31, part = t >> 5;
        float acc0 = 0.f, acc1 = 0.f, acc2 = 0.f, acc3 = 0.f;
        const float* w = W1 + (size_t)(part * 128) * 32 + m;
        const int j0 = part * 128;
        for (int j = 0; j < 128; ++j) {
            const float wv_ = w[(size_t)j * 32];
            acc0 += s_pool2[0][j0 + j] * wv_;
            acc1 += s_pool2[1][j0 + j] * wv_;
            acc2 += s_pool2[2][j0 + j] * wv_;
            acc3 += s_pool2[3][j0 + j] * wv_;
        }
        s_red[(part * 4 + 0) * 32 + m] = acc0;
        s_red[(part * 4 + 1) * 32 + m] = acc1;
        s_red[(part * 4 + 2) * 32 + m] = acc2;
        s_red[(part * 4 + 3) * 32 + m] = acc3;
    }
    __syncthreads();
    if (t < 128) {
        const int g = t >> 5, m = t & 31;
        float s = b1[m];
        #pragma unroll
        for (int p = 0; p < 8; ++p) s += s_red[(p * 4 + g) * 32 + m];
        s_d1[g * 32 + m] = fmaxf(s, 0.f);
    }
    __syncthreads();
    if (t < 64) {
        const int g = t >> 4, dim = t & 15;
        float s = b5[dim];
        #pragma unroll
        for (int m = 0; m < 32; ++m) s += s_d1[g * 32 + m] * W5[m * 16 + dim];
        float c = fmaxf(s, 0.f) * W6[dim];
        c += __shfl_xor(c, 1);
        c += __shfl_xor(c, 2);
        c += __shfl_xor(c, 4);
        c += __shfl_xor(c, 8);
        if (dim == 0) {
            const int b = b0 + g;
            float o = b7[0] + W7[0] * (b6[0] + c);
            const float* ph = inputs + (size_t)b * (A_DIM * F_DIM) + NAF;
            #pragma unroll
            for (int i = 0; i < NPHYS; ++i) o += W7[i + 1] * ph[i];
            out[(size_t)b * 16] = o;
        }
    }
}

// ===== fallback (R11-proven single-kernel pipeline) =====
template <bool USE_WS>
__global__ __launch_bounds__(BLOCK, 4) void pggcn_kernel(
    const float* __restrict__ inputs,
    const int*   __restrict__ i_s,
    const float* __restrict__ W_self,
    const float* __restrict__ W_nei,
    const float* __restrict__ b_r,
    const float* __restrict__ Wc,
    const float* __restrict__ bc,
    const float* __restrict__ W1,
    const float* __restrict__ b1,
    const float* __restrict__ W5,
    const float* __restrict__ b5,
    const float* __restrict__ W6,
    const float* __restrict__ b6,
    const float* __restrict__ W7,
    const float* __restrict__ b7,
    const ushort* __restrict__ wcT,
    float* __restrict__ out)
{
    __shared__ __align__(16) ushort s_hb[MROWS * HPAD];
    __shared__ float s_aggp[6 * 40];
    __shared__ float s_agg[40];
    __shared__ float s_hnei[32];
    __shared__ float s_phys[NPHYS];

    float* s_pool = (float*)s_hb;
    float* s_red  = (float*)s_hb + 1024;
    float* s_d1   = s_red + 256;
    float* s_d5   = s_d1 + 32;

    const int b    = blockIdx.x;
    const int t    = threadIdx.x;
    const int lane = t & 63;
    const int wv   = t >> 6;
    const int lr   = lane & 15;
    const int lg   = lane >> 4;
    const int ns   = i_s[b];
    const int nmt  = (ns + 15) >> 4;
    const float* in_b = inputs + (size_t)b * (A_DIM * F_DIM);

    short8 bws0[2], bws1[2];
    #pragma unroll
    for (int nt = 0; nt < 2; ++nt) {
        const int c = nt * 16 + lr;
        const bool cv_ = (c < R_OUT);
        #pragma unroll
        for (int j = 0; j < 8; ++j) {
            const int k0 = lg * 8 + j;
            const int k1 = 32 + lg * 8 + j;
            bws0[nt][j] = (short)(cv_ ? f2bf(W_self[k0 * R_OUT + c]) : 0);
            bws1[nt][j] = (short)((cv_ && k1 < NAF) ? f2bf(W_self[k1 * R_OUT + c]) : 0);
        }
    }

    if (t < NPHYS) {
        const float p = in_b[NAF + t];
        s_phys[t] = p;
        out[(size_t)b * 16 + 1 + t] = p;
    }

    const int tot = nmt * 16 * HPAD;
    for (int i = t; i < tot; i += BLOCK) {
        const int r = i / HPAD;
        const int f = i - r * HPAD;
        const float v = (r < ns && f < NAF) ? in_b[r * F_DIM + f] : 0.f;
        s_hb[i] = f2bf(v);
    }
    __syncthreads();

    if (t < 240) {
        const int f = t % 40, g = t / 40;
        float s = 0.f;
        for (int r = g; r < ns; r += 6) s += bf2f(s_hb[r * HPAD + f]);
        s_aggp[g * 40 + f] = s;
    }
    __syncthreads();
    if (t < 40) {
        float s = 0.f;
        #pragma unroll
        for (int g = 0; g < 6; ++g) s += s_aggp[g * 40 + t];
        s_agg[t] = s;
    }
    __syncthreads();
    if (t < 32) {
        float s = 0.f;
        if (t < R_OUT) {
            s = b_r[t];
            #pragma unroll
            for (int f = 0; f < NAF; ++f) s += s_agg[f] * W_nei[f * R_OUT + t];
        }
        s_hnei[t] = s;
    }
    __syncthreads();

    for (int mt = wv; mt < nmt; mt += 4) {
        const int ar = mt * 16 + lr;
        const short8 a0 = *(const short8*)&s_hb[ar * HPAD + lg * 8];
        short8 a1 = short8{0, 0, 0, 0, 0, 0, 0, 0};
        if (lg == 0) a1 = *(const short8*)&s_hb[ar * HPAD + 32];
        const float hn0 = s_hnei[lr];
        const float hn1 = s_hnei[16 + lr];
        floatx4 aS0 = {hn0, hn0, hn0, hn0};
        floatx4 aS1 = {hn1, hn1, hn1, hn1};
        aS0 = __builtin_amdgcn_mfma_f32_16x16x32_bf16(a0, bws0[0], aS0, 0, 0, 0);
        aS0 = __builtin_amdgcn_mfma_f32_16x16x32_bf16(a1, bws1[0], aS0, 0, 0, 0);
        aS1 = __builtin_amdgcn_mfma_f32_16x16x32_bf16(a0, bws0[1], aS1, 0, 0, 0);
        aS1 = __builtin_amdgcn_mfma_f32_16x16x32_bf16(a1, bws1[1], aS1, 0, 0, 0);
        #pragma unroll
        for (int q = 0; q < 4; ++q) {
            const int row = mt * 16 + lg * 4 + q;
            const bool v = (row < ns);
            s_hb[row * HPAD + lr]      = v ? f2bf(fmaxf(aS0[q], 0.f)) : (ushort)0;
            s_hb[row * HPAD + 16 + lr] = v ? f2bf(fmaxf(aS1[q], 0.f)) : (ushort)0;
        }
    }

    const float dead = (float)(nmt * 16 - ns);
    float pool[16];
    #pragma unroll
    for (int i = 0; i < 16; ++i) pool[i] = 0.f;

    #pragma unroll 1
    for (int qt = 0; qt < 4; ++qt) {
        short8 bfr[4];
        float  bcv[4];
        #pragma unroll
        for (int nt = 0; nt < 4; ++nt) {
            const int col = wv * 256 + qt * 64 + nt * 16 + lr;
            bcv[nt] = bc[col];
            if (USE_WS) {
                if (lg < 3) bfr[nt] = *(const short8*)&wcT[col * KP + lg * 8];
                else        bfr[nt] = short8{0, 0, 0, 0, 0, 0, 0, 0};
            } else {
                #pragma unroll
                for (int j = 0; j < 8; ++j) {
                    const int k = lg * 8 + j;
                    bfr[nt][j] = (short)((k < R_OUT) ? f2bf(Wc[k * C_OUT + col]) : 0);
                }
            }
        }
        if (qt == 0) __syncthreads();

        for (int mt = 0; mt < nmt; ++mt) {
            const short8 af = *(const short8*)&s_hb[(mt * 16 + lr) * HPAD + lg * 8];
            #pragma unroll
            for (int nt = 0; nt < 4; ++nt) {
                floatx4 acc = { bcv[nt], bcv[nt], bcv[nt], bcv[nt] };
                acc = __builtin_amdgcn_mfma_f32_16x16x32_bf16(af, bfr[nt], acc, 0, 0, 0);
                pool[qt * 4 + nt] += fmaxf(acc[0], 0.f) + fmaxf(acc[1], 0.f)
                                   + fmaxf(acc[2], 0.f) + fmaxf(acc[3], 0.f);
            }
        }
        if (lg == 0) {
            #pragma unroll
            for (int nt = 0; nt < 4; ++nt)
                pool[qt * 4 + nt] -= dead * fmaxf(bcv[nt], 0.f);
        }
    }

    #pragma unroll
    for (int i = 0; i < 16; ++i) {
        float p = pool[i];
        p += __shfl_xor(p, 16);
        p += __shfl_xor(p, 32);
        pool[i] = p;
    }
    __syncthreads();
    if (lg == 0) {
        #pragma unroll
        for (int qt = 0; qt < 4; ++qt)
            #pragma unroll
            for (int nt = 0; nt < 4; ++nt)
                s_pool[wv * 256 + qt * 64 + nt * 16 + lr] = pool[qt * 4 + nt];
    }
    __syncthreads();

    {
        const int m = t & 31, part = t >> 5;
        const float4* pp = (const float4*)&s_pool[part * 128];
        const float* wrow = W1 + (size_t)(part * 128) * 32 + m;
        float s = 0.f;
        #pragma unroll
        for (int jq = 0; jq < 32; ++jq) {
            const float4 pv = pp[jq];
            s += pv.x * wrow[0] + pv.y * wrow[32] + pv.z * wrow[64] + pv.w * wrow[96];
            wrow += 128;
        }
        s_red[part * 32 + m] = s;
    }
    __syncthreads();
    if (t < 32) {
        float s = b1[t];
        #pragma unroll
        for (int p = 0; p < 8; ++p) s += s_red[p * 32 + t];
        s_d1[t] = fmaxf(s, 0.f);
    }
    __syncthreads();
    if (t < 16) {
        float s = b5[t];
        #pragma unroll
        for (int m = 0; m < 32; ++m) s += s_d1[m] * W5[m * 16 + t];
        s_d5[t] = fmaxf(s, 0.f);
    }
    __syncthreads();
    if (t == 0) {
        float mv = b6[0];
        #pragma unroll
        for (int m = 0; m < 16; ++m) mv += s_d5[m] * W6[m];
        float o = b7[0] + W7[0] * mv;
        #pragma unroll
        for (int i = 0; i < NPHYS; ++i) o += W7[i + 1] * s_phys[i];
        out[(size_t)b * 16] = o;
    }
}

extern "C" void kernel_launch(void* const* d_in, const int* in_sizes, int n_in,
                              void* d_out, int out_size, void* d_ws, size_t ws_size,
                              hipStream_t stream) {
    const float* inputs = (const float*)d_in[0];
    const int*   i_s    = (const int*)d_in[1];
    const float* W_self = (const float*)d_in[2];
    const float* W_nei  = (const float*)d_in[3];
    const float* b_r    = (const float*)d_in[4];
    const float* Wc     = (const float*)d_in[5];
    const float* bc     = (const float*)d_in[6];
    const float* W1     = (const float*)d_in[7];
    const float* b1     = (const float*)d_in[8];
    const float* W5     = (const float*)d_in[9];
    const float* b5     = (const float*)d_in[10];
    const float* W6     = (const float*)d_in[11];
    const float* b6     = (const float*)d_in[12];
    const float* W7     = (const float*)d_in[13];
    const float* b7     = (const float*)d_in[14];
    float* out = (float*)d_out;

    const int B = in_sizes[1];   // 1024
    const size_t off_wct   = 0;
    const size_t wct_b     = (size_t)C_OUT * KP * sizeof(ushort);          // 49152
    const size_t off_hnei  = off_wct + wct_b;
    const size_t hnei_b    = (size_t)B * 32 * sizeof(float);               // 131072
    const size_t off_wsf   = off_hnei + hnei_b;
    const size_t wsf_b     = (size_t)64 * 4 * 8 * sizeof(ushort);          // 4096
    const size_t off_pool  = off_wsf + wsf_b;
    const size_t pool_b    = (size_t)NSPL * B * 1024 * sizeof(ushort);     // 8 MiB
    const size_t need      = off_pool + pool_b;

    ushort* wcT    = (ushort*)((char*)d_ws + off_wct);
    float*  hneip  = (float*)((char*)d_ws + off_hnei);
    ushort* wsfrag = (ushort*)((char*)d_ws + off_wsf);
    ushort* poolp  = (ushort*)((char*)d_ws + off_pool);

    if (ws_size >= need && (B % 8) == 0) {
        pggcn_prep<<<B + WCB + 1, BLOCK, 0, stream>>>(inputs, i_s, W_self, W_nei,
            b_r, Wc, hneip, wcT, wsfrag, out, B);
        pggcn_main<<<NSPL * B, BLOCK, 0, stream>>>(inputs, i_s, bc, wcT, wsfrag,
                                                   hneip, poolp, B);
        pggcn_tail<<<B / 4, BLOCK, 0, stream>>>(inputs, poolp, W1, b1, W5, b5,
                                                W6, b6, W7, b7, out, B);
    } else if (ws_size >= wct_b) {
        wc_prep<<<WCB, 256, 0, stream>>>(Wc, wcT);
        pggcn_kernel<true><<<B, BLOCK, 0, stream>>>(inputs, i_s, W_self, W_nei, b_r,
            Wc, bc, W1, b1, W5, b5, W6, b6, W7, b7, wcT, out);
    } else {
        pggcn_kernel<false><<<B, BLOCK, 0, stream>>>(inputs, i_s, W_self, W_nei, b_r,
            Wc, bc, W1, b1, W5, b5, W6, b6, W7, b7, nullptr, out);
    }
}

// Round 19
// 47.851 us; speedup vs baseline: 6.7325x; 1.0463x over previous
//
#include <hip/hip_runtime.h>
#include <hip/hip_bf16.h>

#define A_DIM 200
#define F_DIM 53
#define NAF 38
#define NPHYS 15
#define R_OUT 20
#define C_OUT 1024
#define BLOCK 256
#define PBLK 512     // prep block size
#define HPAD 40      // ushort row stride of LDS tile
#define MROWS 208
#define NSPL 4       // row splits per batch
#define KP 24        // wcT k-stride (k>=20 zeroed)
#define WCB2 ((C_OUT * KP + PBLK - 1) / PBLK)   // 48 wcT chunks at 512 thr

typedef __attribute__((ext_vector_type(8))) short short8;
typedef __attribute__((ext_vector_type(4))) float floatx4;

__device__ __forceinline__ float bf2f(ushort u) { return __uint_as_float((uint)u << 16); }
__device__ __forceinline__ ushort f2bf(float f) {
    union { __hip_bfloat16 h; ushort u; } cv; cv.h = __float2bfloat16(f); return cv.u;
}

// standalone wcT prep (fallback tier only)
__global__ void wc_prep(const float* __restrict__ Wc, ushort* __restrict__ wcT) {
    const int i = blockIdx.x * 256 + threadIdx.x;
    if (i >= C_OUT * KP) return;
    const int col = i / KP, k = i - col * KP;
    wcT[i] = f2bf((k < R_OUT) ? Wc[k * C_OUT + col] : 0.f);
}

// ===== A: [0,nB): agg->hnei+physics | [nB,nB+WCB2): wcT | nB+WCB2: wsfrag =====
__global__ __launch_bounds__(PBLK, 4) void pggcn_prep(
    const float* __restrict__ inputs,
    const int*   __restrict__ i_s,
    const float* __restrict__ W_self,
    const float* __restrict__ W_nei,
    const float* __restrict__ b_r,
    const float* __restrict__ Wc,
    float* __restrict__ hneip,    // [B][32]
    ushort* __restrict__ wcT,     // [1024][24]
    ushort* __restrict__ wsfrag,  // [64][4] short8 = 4 KB
    float* __restrict__ out,
    int nB)
{
    __shared__ float s_aggp[8 * 56];
    __shared__ float s_agg[NAF];
    const int bx = blockIdx.x, t = threadIdx.x;

    if (bx >= nB) {
        if (bx == nB + WCB2) {
            // W_self B-frag table: consumer lane l, frag q (t < 256)
            if (t < 256) {
                const int l = t >> 2, q = t & 3;
                const int lr = l & 15, lg = l >> 4;
                const int nt = q & 1, ks = q >> 1;
                const int c = nt * 16 + lr;
                short8 v;
                #pragma unroll
                for (int j = 0; j < 8; ++j) {
                    const int k = ks * 32 + lg * 8 + j;
                    const bool p = (c < R_OUT) && (k < NAF);
                    v[j] = (short)(p ? f2bf(W_self[k * R_OUT + c]) : 0);
                }
                *(short8*)&wsfrag[(size_t)t * 8] = v;
            }
            return;
        }
        const int i = (bx - nB) * PBLK + t;   // wcT conversion chunk
        if (i < C_OUT * KP) {
            const int col = i / KP, k = i - col * KP;
            wcT[i] = f2bf((k < R_OUT) ? Wc[k * C_OUT + col] : 0.f);
        }
        return;
    }

    const int b = bx;
    const int ns = i_s[b];
    const float* in_b = inputs + (size_t)b * (A_DIM * F_DIM);

    if (t < NPHYS) out[(size_t)b * 16 + 1 + t] = in_b[NAF + t];

    // 8 row-groups x 53 cols, 4-deep batched loads (halved dependent chain)
    if (t < 8 * F_DIM) {
        const int g = t / F_DIM, c = t - g * F_DIM;
        const float* p = in_b + g * F_DIM + c;
        float s = 0.f;
        int r = g;
        for (; r + 32 <= ns; r += 32) {
            const float v0 = p[0], v1 = p[8 * F_DIM], v2 = p[16 * F_DIM], v3 = p[24 * F_DIM];
            s += (v0 + v1) + (v2 + v3);
            p += 32 * F_DIM;
        }
        for (; r < ns; r += 8) { s += *p; p += 8 * F_DIM; }
        s_aggp[g * 56 + c] = s;
    }
    __syncthreads();
    if (t < NAF) {
        float s = ((s_aggp[t] + s_aggp[56 + t]) + (s_aggp[112 + t] + s_aggp[168 + t]))
                + ((s_aggp[224 + t] + s_aggp[280 + t]) + (s_aggp[336 + t] + s_aggp[392 + t]));
        s_agg[t] = s;
    }
    __syncthreads();
    if (t < 32) {
        float s = 0.f;
        if (t < R_OUT) {
            s = b_r[t];
            #pragma unroll
            for (int f = 0; f < NAF; ++f) s += s_agg[f] * W_nei[f * R_OUT + t];
        }
        hneip[(size_t)b * 32 + t] = s;
    }
}

// ===== B: row-quarter blocks -> partial pooled (bf16) to pooledp[split][b][1024]
//       (byte-identical to R15's proven 48.3 µs main) =====
__global__ __launch_bounds__(256, 8) void pggcn_main(
    const float* __restrict__ inputs,
    const int*   __restrict__ i_s,
    const float* __restrict__ bc,
    const ushort* __restrict__ wcT,
    const ushort* __restrict__ wsfrag,
    const float* __restrict__ hneip,
    ushort* __restrict__ pooledp,
    int nB)
{
    __shared__ __align__(16) ushort s_hb[64 * HPAD];   // 5120 B (atoms -> h in place)
    float* s_pool = (float*)s_hb;                      // 1024 f alias (post-main)

    const int bx    = blockIdx.x;
    const int split = bx / nB;           // 0..3 (split-major keeps batch on one XCD)
    const int b     = bx - split * nB;
    const int t     = threadIdx.x;
    const int lane  = t & 63;
    const int wv    = t >> 6;
    const int lr    = lane & 15;
    const int lg    = lane >> 4;
    const int ns    = i_s[b];
    const int nmt   = (ns + 15) >> 4;
    const int lt0   = (nmt * split) >> 2;
    const int lt1   = (nmt * (split + 1)) >> 2;
    const int ntl   = lt1 - lt0;         // 0..4 tiles
    ushort* outp = pooledp + ((size_t)(split * nB + b)) * 1024;

    if (ntl <= 0) {   // no rows: publish exact zeros (block-uniform, no barriers)
        ushort4 z = {0, 0, 0, 0};
        ((ushort4*)outp)[t] = z;
        return;
    }
    const int row0  = lt0 * 16;
    const int nrows = ntl * 16;
    const float* in_b = inputs + (size_t)b * (A_DIM * F_DIM);

    const float hn0 = hneip[(size_t)b * 32 + lr];
    const float hn1 = hneip[(size_t)b * 32 + 16 + lr];

    // W_self B-frags: 4 coalesced 16B loads from the precomputed table
    const short8 bws00 = *(const short8*)&wsfrag[(size_t)(lane * 4 + 0) * 8];
    const short8 bws01 = *(const short8*)&wsfrag[(size_t)(lane * 4 + 1) * 8];
    const short8 bws10 = *(const short8*)&wsfrag[(size_t)(lane * 4 + 2) * 8];
    const short8 bws11 = *(const short8*)&wsfrag[(size_t)(lane * 4 + 3) * 8];

    // ---- stage valid rows bf16, thread-per-row-quad: r = t>>2, f = (t&3)*10..+9 ----
    const int vloc = (ns - row0 < nrows) ? (ns - row0) : nrows;
    {
        const int r = t >> 2, q = t & 3;
        if (r < vloc) {
            const float* rp = in_b + (size_t)(row0 + r) * F_DIM + q * 10;
            uint* dst = (uint*)&s_hb[r * HPAD + q * 10];
            #pragma unroll
            for (int p = 0; p < 5; ++p) {
                const uint lo = f2bf(rp[2 * p]);
                const uint hi = f2bf(rp[2 * p + 1]);
                dst[p] = lo | (hi << 16);
            }
        }
    }
    __syncthreads();

    // ---- h-MFMA in place: h = (row valid) ? relu(atom@W_self + hnei) : 0 ----
    for (int lt = wv; lt < ntl; lt += 4) {
        const int ar = lt * 16 + lr;
        const short8 a0 = *(const short8*)&s_hb[ar * HPAD + lg * 8];
        short8 a1 = short8{0, 0, 0, 0, 0, 0, 0, 0};
        if (lg == 0) a1 = *(const short8*)&s_hb[ar * HPAD + 32];
        floatx4 aS0 = {hn0, hn0, hn0, hn0};
        floatx4 aS1 = {hn1, hn1, hn1, hn1};
        aS0 = __builtin_amdgcn_mfma_f32_16x16x32_bf16(a0, bws00, aS0, 0, 0, 0);
        aS0 = __builtin_amdgcn_mfma_f32_16x16x32_bf16(a1, bws10, aS0, 0, 0, 0);
        aS1 = __builtin_amdgcn_mfma_f32_16x16x32_bf16(a0, bws01, aS1, 0, 0, 0);
        aS1 = __builtin_amdgcn_mfma_f32_16x16x32_bf16(a1, bws11, aS1, 0, 0, 0);
        // C/D: col = lane&15, row = (lane>>4)*4 + q
        #pragma unroll
        for (int q = 0; q < 4; ++q) {
            const int lrow = lt * 16 + lg * 4 + q;
            const bool vv = lrow < vloc;
            s_hb[lrow * HPAD + lr]      = vv ? f2bf(fmaxf(aS0[q], 0.f)) : (ushort)0;
            s_hb[lrow * HPAD + 16 + lr] = vv ? f2bf(fmaxf(aS1[q], 0.f)) : (ushort)0;
        }
    }

    // ---- main: partial pooled over own rows, all 1024 cols (4 rounds x 4) ----
    const float dead = (float)(nrows - vloc);
    float pool[16];
    #pragma unroll
    for (int i = 0; i < 16; ++i) pool[i] = 0.f;

    #pragma unroll 1
    for (int qt = 0; qt < 4; ++qt) {
        short8 bfr[4];
        float  bcv[4];
        #pragma unroll
        for (int nt = 0; nt < 4; ++nt) {
            const int col = wv * 256 + qt * 64 + nt * 16 + lr;
            bcv[nt] = bc[col];
            if (lg < 3) bfr[nt] = *(const short8*)&wcT[col * KP + lg * 8];
            else        bfr[nt] = short8{0, 0, 0, 0, 0, 0, 0, 0};
        }
        if (qt == 0) __syncthreads();   // h ready; frag-load latency overlapped

        for (int mt = 0; mt < ntl; ++mt) {
            const short8 af = *(const short8*)&s_hb[(mt * 16 + lr) * HPAD + lg * 8];
            #pragma unroll
            for (int nt = 0; nt < 4; ++nt) {
                floatx4 acc = { bcv[nt], bcv[nt], bcv[nt], bcv[nt] };
                acc = __builtin_amdgcn_mfma_f32_16x16x32_bf16(af, bfr[nt], acc, 0, 0, 0);
                pool[qt * 4 + nt] += fmaxf(acc[0], 0.f) + fmaxf(acc[1], 0.f)
                                   + fmaxf(acc[2], 0.f) + fmaxf(acc[3], 0.f);
            }
        }
        if (lg == 0) {   // local dead rows contributed relu(bc) each
            #pragma unroll
            for (int nt = 0; nt < 4; ++nt)
                pool[qt * 4 + nt] -= dead * fmaxf(bcv[nt], 0.f);
        }
    }
    #pragma unroll
    for (int i = 0; i < 16; ++i) {
        float p = pool[i];
        p += __shfl_xor(p, 16);
        p += __shfl_xor(p, 32);
        pool[i] = p;
    }
    __syncthreads();   // all s_hb reads done; alias safe
    if (lg == 0) {
        #pragma unroll
        for (int qt = 0; qt < 4; ++qt)
            #pragma unroll
            for (int nt = 0; nt < 4; ++nt)
                s_pool[wv * 256 + qt * 64 + nt * 16 + lr] = pool[qt * 4 + nt];
    }
    __syncthreads();

    // ---- pack bf16 + one coalesced store ----
    {
        const float4 pv = ((const float4*)s_pool)[t];
        ushort4 o;
        o.x = f2bf(pv.x); o.y = f2bf(pv.y); o.z = f2bf(pv.z); o.w = f2bf(pv.w);
        ((ushort4*)outp)[t] = o;
    }
}

// ===== C: tail — 2 batches/block (R15-proven): sum 4 splits; d1; d5; out0 =====
__global__ __launch_bounds__(256, 4) void pggcn_tail(
    const float* __restrict__ inputs,
    const ushort* __restrict__ pooledp,
    const float* __restrict__ W1,
    const float* __restrict__ b1,
    const float* __restrict__ W5,
    const float* __restrict__ b5,
    const float* __restrict__ W6,
    const float* __restrict__ b6,
    const float* __restrict__ W7,
    const float* __restrict__ b7,
    float* __restrict__ out, int nB)
{
    __shared__ float s_pool2[2][1024];   // 8 KB
    __shared__ float s_red[8 * 2 * 32];  // 2 KB
    __shared__ float s_d1[2 * 32];
    const int t = threadIdx.x;
    const int b0 = blockIdx.x * 2;

    // sum the 4 split partials (bf16 -> fp32)
    #pragma unroll
    for (int g = 0; g < 2; ++g) {
        const uint* q0 = (const uint*)(pooledp + (size_t)(0 * nB + b0 + g) * 1024);
        const uint* q1 = (const uint*)(pooledp + (size_t)(1 * nB + b0 + g) * 1024);
        const uint* q2 = (const uint*)(pooledp + (size_t)(2 * nB + b0 + g) * 1024);
        const uint* q3 = (const uint*)(pooledp + (size_t)(3 * nB + b0 + g) * 1024);
        for (int i = t; i < 512; i += 256) {
            const uint u0 = q0[i], u1 = q1[i], u2 = q2[i], u3 = q3[i];
            s_pool2[g][2 * i] = (bf2f((ushort)u0) + bf2f((ushort)u1))
                              + (bf2f((ushort)u2) + bf2f((ushort)u3));
            s_pool2[g][2 * i + 1] = (bf2f((ushort)(u0 >> 16)) + bf2f((ushort)(u1 >> 16)))
                                  + (bf2f((ushort)(u2 >> 16)) + bf2f((ushort)(u3 >> 16)));
        }
    }
    __syncthreads();

    // d1 partials: thread (m, part of 8) accumulates 2 batches at once
    {
        const int m = t & 31, part = t >> 5;
        float acc0 = 0.f, acc1 = 0.f;
        const float* w = W1 + (size_t)(part * 128) * 32 + m;
        const int j0 = part * 128;
        for (int j = 0; j < 128; ++j) {
            const float wv_ = w[(size_t)j * 32];
            acc0 += s_pool2[0][j0 + j] * wv_;
            acc1 += s_pool2[1][j0 + j] * wv_;
        }
        s_red[(part * 2 + 0) * 32 + m] = acc0;
        s_red[(part * 2 + 1) * 32 + m] = acc1;
    }
    __syncthreads();
    if (t < 64) {
        const int g = t >> 5, m = t & 31;
        float s = b1[m];
        #pragma unroll
        for (int p = 0; p < 8; ++p) s += s_red[(p * 2 + g) * 32 + m];
        s_d1[g * 32 + m] = fmaxf(s, 0.f);
    }
    __syncthreads();
    if (t < 32) {
        const int g = t >> 4, dim = t & 15;
        float s = b5[dim];
        #pragma unroll
        for (int m = 0; m < 32; ++m) s += s_d1[g * 32 + m] * W5[m * 16 + dim];
        float c = fmaxf(s, 0.f) * W6[dim];
        c += __shfl_xor(c, 1);
        c += __shfl_xor(c, 2);
        c += __shfl_xor(c, 4);
        c += __shfl_xor(c, 8);
        if (dim == 0) {
            const int b = b0 + g;
            float o = b7[0] + W7[0] * (b6[0] + c);
            const float* ph = inputs + (size_t)b * (A_DIM * F_DIM) + NAF;
            #pragma unroll
            for (int i = 0; i < NPHYS; ++i) o += W7[i + 1] * ph[i];
            out[(size_t)b * 16] = o;
        }
    }
}

// ===== fallback (R11-proven single-kernel pipeline) =====
template <bool USE_WS>
__global__ __launch_bounds__(BLOCK, 4) void pggcn_kernel(
    const float* __restrict__ inputs,
    const int*   __restrict__ i_s,
    const float* __restrict__ W_self,
    const float* __restrict__ W_nei,
    const float* __restrict__ b_r,
    const float* __restrict__ Wc,
    const float* __restrict__ bc,
    const float* __restrict__ W1,
    const float* __restrict__ b1,
    const float* __restrict__ W5,
    const float* __restrict__ b5,
    const float* __restrict__ W6,
    const float* __restrict__ b6,
    const float* __restrict__ W7,
    const float* __restrict__ b7,
    const ushort* __restrict__ wcT,
    float* __restrict__ out)
{
    __shared__ __align__(16) ushort s_hb[MROWS * HPAD];
    __shared__ float s_aggp[6 * 40];
    __shared__ float s_agg[40];
    __shared__ float s_hnei[32];
    __shared__ float s_phys[NPHYS];

    float* s_pool = (float*)s_hb;
    float* s_red  = (float*)s_hb + 1024;
    float* s_d1   = s_red + 256;
    float* s_d5   = s_d1 + 32;

    const int b    = blockIdx.x;
    const int t    = threadIdx.x;
    const int lane = t & 63;
    const int wv   = t >> 6;
    const int lr   = lane & 15;
    const int lg   = lane >> 4;
    const int ns   = i_s[b];
    const int nmt  = (ns + 15) >> 4;
    const float* in_b = inputs + (size_t)b * (A_DIM * F_DIM);

    short8 bws0[2], bws1[2];
    #pragma unroll
    for (int nt = 0; nt < 2; ++nt) {
        const int c = nt * 16 + lr;
        const bool cv_ = (c < R_OUT);
        #pragma unroll
        for (int j = 0; j < 8; ++j) {
            const int k0 = lg * 8 + j;
            const int k1 = 32 + lg * 8 + j;
            bws0[nt][j] = (short)(cv_ ? f2bf(W_self[k0 * R_OUT + c]) : 0);
            bws1[nt][j] = (short)((cv_ && k1 < NAF) ? f2bf(W_self[k1 * R_OUT + c]) : 0);
        }
    }

    if (t < NPHYS) {
        const float p = in_b[NAF + t];
        s_phys[t] = p;
        out[(size_t)b * 16 + 1 + t] = p;
    }

    const int tot = nmt * 16 * HPAD;
    for (int i = t; i < tot; i += BLOCK) {
        const int r = i / HPAD;
        const int f = i - r * HPAD;
        const float v = (r < ns && f < NAF) ? in_b[r * F_DIM + f] : 0.f;
        s_hb[i] = f2bf(v);
    }
    __syncthreads();

    if (t < 240) {
        const int f = t % 40, g = t / 40;
        float s = 0.f;
        for (int r = g; r < ns; r += 6) s += bf2f(s_hb[r * HPAD + f]);
        s_aggp[g * 40 + f] = s;
    }
    __syncthreads();
    if (t < 40) {
        float s = 0.f;
        #pragma unroll
        for (int g = 0; g < 6; ++g) s += s_aggp[g * 40 + t];
        s_agg[t] = s;
    }
    __syncthreads();
    if (t < 32) {
        float s = 0.f;
        if (t < R_OUT) {
            s = b_r[t];
            #pragma unroll
            for (int f = 0; f < NAF; ++f) s += s_agg[f] * W_nei[f * R_OUT + t];
        }
        s_hnei[t] = s;
    }
    __syncthreads();

    for (int mt = wv; mt < nmt; mt += 4) {
        const int ar = mt * 16 + lr;
        const short8 a0 = *(const short8*)&s_hb[ar * HPAD + lg * 8];
        short8 a1 = short8{0, 0, 0, 0, 0, 0, 0, 0};
        if (lg == 0) a1 = *(const short8*)&s_hb[ar * HPAD + 32];
        const float hn0 = s_hnei[lr];
        const float hn1 = s_hnei[16 + lr];
        floatx4 aS0 = {hn0, hn0, hn0, hn0};
        floatx4 aS1 = {hn1, hn1, hn1, hn1};
        aS0 = __builtin_amdgcn_mfma_f32_16x16x32_bf16(a0, bws0[0], aS0, 0, 0, 0);
        aS0 = __builtin_amdgcn_mfma_f32_16x16x32_bf16(a1, bws1[0], aS0, 0, 0, 0);
        aS1 = __builtin_amdgcn_mfma_f32_16x16x32_bf16(a0, bws0[1], aS1, 0, 0, 0);
        aS1 = __builtin_amdgcn_mfma_f32_16x16x32_bf16(a1, bws1[1], aS1, 0, 0, 0);
        #pragma unroll
        for (int q = 0; q < 4; ++q) {
            const int row = mt * 16 + lg * 4 + q;
            const bool v = (row < ns);
            s_hb[row * HPAD + lr]      = v ? f2bf(fmaxf(aS0[q], 0.f)) : (ushort)0;
            s_hb[row * HPAD + 16 + lr] = v ? f2bf(fmaxf(aS1[q], 0.f)) : (ushort)0;
        }
    }

    const float dead = (float)(nmt * 16 - ns);
    float pool[16];
    #pragma unroll
    for (int i = 0; i < 16; ++i) pool[i] = 0.f;

    #pragma unroll 1
    for (int qt = 0; qt < 4; ++qt) {
        short8 bfr[4];
        float  bcv[4];
        #pragma unroll
        for (int nt = 0; nt < 4; ++nt) {
            const int col = wv * 256 + qt * 64 + nt * 16 + lr;
            bcv[nt] = bc[col];
            if (USE_WS) {
                if (lg < 3) bfr[nt] = *(const short8*)&wcT[col * KP + lg * 8];
                else        bfr[nt] = short8{0, 0, 0, 0, 0, 0, 0, 0};
            } else {
                #pragma unroll
                for (int j = 0; j < 8; ++j) {
                    const int k = lg * 8 + j;
                    bfr[nt][j] = (short)((k < R_OUT) ? f2bf(Wc[k * C_OUT + col]) : 0);
                }
            }
        }
        if (qt == 0) __syncthreads();

        for (int mt = 0; mt < nmt; ++mt) {
            const short8 af = *(const short8*)&s_hb[(mt * 16 + lr) * HPAD + lg * 8];
            #pragma unroll
            for (int nt = 0; nt < 4; ++nt) {
                floatx4 acc = { bcv[nt], bcv[nt], bcv[nt], bcv[nt] };
                acc = __builtin_amdgcn_mfma_f32_16x16x32_bf16(af, bfr[nt], acc, 0, 0, 0);
                pool[qt * 4 + nt] += fmaxf(acc[0], 0.f) + fmaxf(acc[1], 0.f)
                                   + fmaxf(acc[2], 0.f) + fmaxf(acc[3], 0.f);
            }
        }
        if (lg == 0) {
            #pragma unroll
            for (int nt = 0; nt < 4; ++nt)
                pool[qt * 4 + nt] -= dead * fmaxf(bcv[nt], 0.f);
        }
    }

    #pragma unroll
    for (int i = 0; i < 16; ++i) {
        float p = pool[i];
        p += __shfl_xor(p, 16);
        p += __shfl_xor(p, 32);
        pool[i] = p;
    }
    __syncthreads();
    if (lg == 0) {
        #pragma unroll
        for (int qt = 0; qt < 4; ++qt)
            #pragma unroll
            for (int nt = 0; nt < 4; ++nt)
                s_pool[wv * 256 + qt * 64 + nt * 16 + lr] = pool[qt * 4 + nt];
    }
    __syncthreads();

    {
        const int m = t & 31, part = t >> 5;
        const float4* pp = (const float4*)&s_pool[part * 128];
        const float* wrow = W1 + (size_t)(part * 128) * 32 + m;
        float s = 0.f;
        #pragma unroll
        for (int jq = 0; jq < 32; ++jq) {
            const float4 pv = pp[jq];
            s += pv.x * wrow[0] + pv.y * wrow[32] + pv.z * wrow[64] + pv.w * wrow[96];
            wrow += 128;
        }
        s_red[part * 32 + m] = s;
    }
    __syncthreads();
    if (t < 32) {
        float s = b1[t];
        #pragma unroll
        for (int p = 0; p < 8; ++p) s += s_red[p * 32 + t];
        s_d1[t] = fmaxf(s, 0.f);
    }
    __syncthreads();
    if (t < 16) {
        float s = b5[t];
        #pragma unroll
        for (int m = 0; m < 32; ++m) s += s_d1[m] * W5[m * 16 + t];
        s_d5[t] = fmaxf(s, 0.f);
    }
    __syncthreads();
    if (t == 0) {
        float mv = b6[0];
        #pragma unroll
        for (int m = 0; m < 16; ++m) mv += s_d5[m] * W6[m];
        float o = b7[0] + W7[0] * mv;
        #pragma unroll
        for (int i = 0; i < NPHYS; ++i) o += W7[i + 1] * s_phys[i];
        out[(size_t)b * 16] = o;
    }
}

extern "C" void kernel_launch(void* const* d_in, const int* in_sizes, int n_in,
                              void* d_out, int out_size, void* d_ws, size_t ws_size,
                              hipStream_t stream) {
    const float* inputs = (const float*)d_in[0];
    const int*   i_s    = (const int*)d_in[1];
    const float* W_self = (const float*)d_in[2];
    const float* W_nei  = (const float*)d_in[3];
    const float* b_r    = (const float*)d_in[4];
    const float* Wc     = (const float*)d_in[5];
    const float* bc     = (const float*)d_in[6];
    const float* W1     = (const float*)d_in[7];
    const float* b1     = (const float*)d_in[8];
    const float* W5     = (const float*)d_in[9];
    const float* b5     = (const float*)d_in[10];
    const float* W6     = (const float*)d_in[11];
    const float* b6     = (const float*)d_in[12];
    const float* W7     = (const float*)d_in[13];
    const float* b7     = (const float*)d_in[14];
    float* out = (float*)d_out;

    const int B = in_sizes[1];   // 1024
    const size_t off_wct   = 0;
    const size_t wct_b     = (size_t)C_OUT * KP * sizeof(ushort);          // 49152
    const size_t off_hnei  = off_wct + wct_b;
    const size_t hnei_b    = (size_t)B * 32 * sizeof(float);               // 131072
    const size_t off_wsf   = off_hnei + hnei_b;
    const size_t wsf_b     = (size_t)64 * 4 * 8 * sizeof(ushort);          // 4096
    const size_t off_pool  = off_wsf + wsf_b;
    const size_t pool_b    = (size_t)NSPL * B * 1024 * sizeof(ushort);     // 8 MiB
    const size_t need      = off_pool + pool_b;

    ushort* wcT    = (ushort*)((char*)d_ws + off_wct);
    float*  hneip  = (float*)((char*)d_ws + off_hnei);
    ushort* wsfrag = (ushort*)((char*)d_ws + off_wsf);
    ushort* poolp  = (ushort*)((char*)d_ws + off_pool);

    if (ws_size >= need && (B % 8) == 0) {
        pggcn_prep<<<B + WCB2 + 1, PBLK, 0, stream>>>(inputs, i_s, W_self, W_nei,
            b_r, Wc, hneip, wcT, wsfrag, out, B);
        pggcn_main<<<NSPL * B, BLOCK, 0, stream>>>(inputs, i_s, bc, wcT, wsfrag,
                                                   hneip, poolp, B);
        pggcn_tail<<<B / 2, BLOCK, 0, stream>>>(inputs, poolp, W1, b1, W5, b5,
                                                W6, b6, W7, b7, out, B);
    } else if (ws_size >= wct_b) {
        wc_prep<<<(C_OUT * KP + 255) / 256, 256, 0, stream>>>(Wc, wcT);
        pggcn_kernel<true><<<B, BLOCK, 0, stream>>>(inputs, i_s, W_self, W_nei, b_r,
            Wc, bc, W1, b1, W5, b5, W6, b6, W7, b7, wcT, out);
    } else {
        pggcn_kernel<false><<<B, BLOCK, 0, stream>>>(inputs, i_s, W_self, W_nei, b_r,
            Wc, bc, W1, b1, W5, b5, W6, b6, W7, b7, nullptr, out);
    }
}